// Round 1
// baseline (2809.325 us; speedup 1.0000x reference)
//
#include <hip/hip_runtime.h>
#include <stdint.h>

#define S_LEN 1500
#define D_MODEL 1280
#define N_HEAD 20
#define D_HEAD 64
#define FF_DIM 5120
#define N_LAYER 4

typedef int v4i __attribute__((ext_vector_type(4)));
typedef short v8s __attribute__((ext_vector_type(8)));
typedef float v4f __attribute__((ext_vector_type(4)));

// ---------------- helpers ----------------

__device__ inline float gelu_tanh(float x) {
    // jax.nn.gelu default (approximate=True)
    float x3 = x * x * x;
    return 0.5f * x * (1.0f + tanhf(0.7978845608028654f * (x + 0.044715f * x3)));
}

__device__ inline float wred_sum(float v) {
    for (int o = 32; o > 0; o >>= 1) v += __shfl_down(v, o, 64);
    return v;
}
__device__ inline float wred_max(float v) {
    for (int o = 32; o > 0; o >>= 1) v = fmaxf(v, __shfl_down(v, o, 64));
    return v;
}
// blockDim.x == 256 (4 waves) assumed
__device__ inline float block_sum(float v, float* sm4) {
    v = wred_sum(v);
    int w = threadIdx.x >> 6;
    if ((threadIdx.x & 63) == 0) sm4[w] = v;
    __syncthreads();
    float r = sm4[0] + sm4[1] + sm4[2] + sm4[3];
    __syncthreads();
    return r;
}
__device__ inline float block_max(float v, float* sm4) {
    v = wred_max(v);
    int w = threadIdx.x >> 6;
    if ((threadIdx.x & 63) == 0) sm4[w] = v;
    __syncthreads();
    float r = fmaxf(fmaxf(sm4[0], sm4[1]), fmaxf(sm4[2], sm4[3]));
    __syncthreads();
    return r;
}

// f32 -> bf16 round-to-nearest-even, and back
__device__ inline unsigned short f2bf(float x) {
    unsigned int u = __float_as_uint(x);
    u += 0x7fffu + ((u >> 16) & 1u);
    return (unsigned short)(u >> 16);
}
__device__ inline float bf2f(unsigned short h) {
    return __uint_as_float(((unsigned int)h) << 16);
}

// ---------------- conv stem: im2col + split-bf16 MFMA GEMM ----------------
// f32 operands are split x = hi + lo (both bf16, RNE). GEMM computes
// Ah*Bh + Al*Bh + Ah*Bl on the bf16 matrix cores with f32 accumulation;
// residual error ~2^-18 relative (f32-equivalent accuracy).

// A1[t][tap*128+i] = in[i][t-1+tap], t in [0,3000)  (hi/lo bf16 planes)
__global__ __launch_bounds__(256) void im2col1_kernel(
    const float* __restrict__ x, unsigned short* __restrict__ Ah,
    unsigned short* __restrict__ Al)
{
    int t = blockIdx.x * 256 + threadIdx.x;
    int col = blockIdx.y;  // 0..383
    if (t >= 3000) return;
    int tap = col >> 7, i = col & 127;
    int src = t - 1 + tap;
    float v = (src >= 0 && src < 3000) ? x[(size_t)i * 3000 + src] : 0.0f;
    unsigned short h = f2bf(v);
    Ah[(size_t)t * 384 + col] = h;
    Al[(size_t)t * 384 + col] = f2bf(v - bf2f(h));
}

// A2[t][tap*1280+o] = g1[2t-1+tap][o], t in [0,1500)  (hi/lo bf16 planes)
__global__ __launch_bounds__(256) void im2col2_kernel(
    const float* __restrict__ g1, unsigned short* __restrict__ Ah,
    unsigned short* __restrict__ Al)
{
    int col = blockIdx.x * 256 + threadIdx.x;  // 0..3839
    int t = blockIdx.y;
    if (col >= 3840) return;
    int tap = col / 1280, o = col - tap * 1280;
    int src = 2 * t - 1 + tap;
    float v = (src >= 0 && src < 3000) ? g1[(size_t)src * 1280 + o] : 0.0f;
    unsigned short h = f2bf(v);
    Ah[(size_t)t * 3840 + col] = h;
    Al[(size_t)t * 3840 + col] = f2bf(v - bf2f(h));
}

// out[o][tap*C+i] = w[o][i][tap]  (hi/lo bf16 planes)
__global__ __launch_bounds__(256) void wreorder_kernel(
    const float* __restrict__ w, unsigned short* __restrict__ woh,
    unsigned short* __restrict__ wol, int C)
{
    int o = blockIdx.x;
    int KC = 3 * C;
    const float* wr = w + (size_t)o * KC;
    for (int col = threadIdx.x; col < KC; col += 256) {
        int tap = col / C, i = col - tap * C;
        float v = wr[i * 3 + tap];
        unsigned short h = f2bf(v);
        woh[(size_t)o * KC + col] = h;
        wol[(size_t)o * KC + col] = f2bf(v - bf2f(h));
    }
}

// C[m][n] = gelu(A[m,:].W[n,:] + bias[n]) (+ pos[m][n] if EPI==1)
// 64x64 block tile, 4 waves (16 rows each), direct global loads, no LDS.
// mfma_f32_16x16x32_bf16: A lane(l15)=m-row, quad*8 = k-offset; B same over n-rows.
template <int EPI>
__global__ __launch_bounds__(256) void gemm_bf16x3_kernel(
    const unsigned short* __restrict__ Ah, const unsigned short* __restrict__ Al,
    const unsigned short* __restrict__ Wh, const unsigned short* __restrict__ Wl,
    const float* __restrict__ bias, const float* __restrict__ pos,
    float* __restrict__ out, int M, int N, int K)
{
    int lane = threadIdx.x & 63;
    int wv = threadIdx.x >> 6;
    int l15 = lane & 15;
    int quad = lane >> 4;
    int m_base = blockIdx.y * 64 + wv * 16;
    int n_base = blockIdx.x * 64;

    int ar = m_base + l15; if (ar >= M) ar = M - 1;
    const unsigned short* aph = Ah + (size_t)ar * K + quad * 8;
    const unsigned short* apl = Al + (size_t)ar * K + quad * 8;
    const unsigned short* bph = Wh + (size_t)(n_base + l15) * K + quad * 8;
    const unsigned short* bpl = Wl + (size_t)(n_base + l15) * K + quad * 8;
    size_t rowK16 = (size_t)16 * K;

    v4f acc[4];
    #pragma unroll
    for (int nb = 0; nb < 4; nb++) acc[nb] = (v4f){0.0f, 0.0f, 0.0f, 0.0f};

    int nsteps = K >> 5;
    for (int s = 0; s < nsteps; s++) {
        v8s ah = *(const v8s*)(aph + s * 32);
        v8s al = *(const v8s*)(apl + s * 32);
        #pragma unroll
        for (int nb = 0; nb < 4; nb++) {
            v8s bh = *(const v8s*)(bph + (size_t)nb * rowK16 + s * 32);
            v8s bl = *(const v8s*)(bpl + (size_t)nb * rowK16 + s * 32);
            acc[nb] = __builtin_amdgcn_mfma_f32_16x16x32_bf16(ah, bh, acc[nb], 0, 0, 0);
            acc[nb] = __builtin_amdgcn_mfma_f32_16x16x32_bf16(al, bh, acc[nb], 0, 0, 0);
            acc[nb] = __builtin_amdgcn_mfma_f32_16x16x32_bf16(ah, bl, acc[nb], 0, 0, 0);
        }
    }

    #pragma unroll
    for (int nb = 0; nb < 4; nb++) {
        int n = n_base + nb * 16 + l15;
        float bn = bias[n];
        #pragma unroll
        for (int r = 0; r < 4; r++) {
            int m = m_base + quad * 4 + r;
            if (m < M) {
                float v = gelu_tanh(acc[nb][r] + bn);
                if (EPI == 1) v += pos[(size_t)m * N + n];
                out[(size_t)m * N + n] = v;
            }
        }
    }
}

// ---------------- quantization kernels ----------------

// per-row weight quant: block per row, float4
__global__ __launch_bounds__(256) void wquant_kernel(
    const float* __restrict__ w, int8_t* __restrict__ qw,
    float* __restrict__ ws, int K)
{
    int r = blockIdx.x;
    int tid = threadIdx.x;
    __shared__ float sm4[4];
    const float4* wr = (const float4*)(w + (size_t)r * K);
    int n4 = K >> 2;
    float mx = 0.0f;
    for (int i = tid; i < n4; i += 256) {
        float4 v = wr[i];
        mx = fmaxf(mx, fmaxf(fmaxf(fabsf(v.x), fabsf(v.y)), fmaxf(fabsf(v.z), fabsf(v.w))));
    }
    mx = block_max(mx, sm4);
    float sc = fmaxf(mx / 127.0f, 1e-8f);
    if (tid == 0) ws[r] = sc;
    float rs = 1.0f / sc;
    char4* qr = (char4*)(qw + (size_t)r * K);
    for (int i = tid; i < n4; i += 256) {
        float4 v = wr[i];
        char4 q;
        q.x = (int8_t)fminf(fmaxf(rintf(v.x * rs), -128.0f), 127.0f);
        q.y = (int8_t)fminf(fmaxf(rintf(v.y * rs), -128.0f), 127.0f);
        q.z = (int8_t)fminf(fmaxf(rintf(v.z * rs), -128.0f), 127.0f);
        q.w = (int8_t)fminf(fmaxf(rintf(v.w * rs), -128.0f), 127.0f);
        qr[i] = q;
    }
}

// RMSNorm + per-token quant, D=1280, block per token
__global__ __launch_bounds__(256) void rmsnorm_quant_kernel(
    const float* __restrict__ x, const float* __restrict__ w,
    const float* __restrict__ b, int8_t* __restrict__ q,
    float* __restrict__ sx)
{
    int s = blockIdx.x;
    int tid = threadIdx.x;
    __shared__ float sm4[4];
    const float* xr = x + (size_t)s * D_MODEL;
    float v[5];
    float ss = 0.0f;
    for (int i = 0; i < 5; i++) {
        float t = xr[tid + 256 * i];
        v[i] = t;
        ss += t * t;
    }
    ss = block_sum(ss, sm4);
    float inv = rsqrtf(ss * (1.0f / 1280.0f) + 1e-6f);
    float mx = 0.0f;
    for (int i = 0; i < 5; i++) {
        int idx = tid + 256 * i;
        float t = v[i] * inv * w[idx] + b[idx];
        v[i] = t;
        mx = fmaxf(mx, fabsf(t));
    }
    mx = block_max(mx, sm4);
    float sc = fmaxf(mx / 127.0f, 1e-8f);
    if (tid == 0) sx[s] = sc;
    float rs = 1.0f / sc;
    for (int i = 0; i < 5; i++) {
        float qv = rintf(v[i] * rs);
        qv = fminf(fmaxf(qv, -128.0f), 127.0f);
        q[(size_t)s * D_MODEL + tid + 256 * i] = (int8_t)qv;
    }
}

// per-token quant (optionally fused gelu); block per token
template <bool GELU>
__global__ __launch_bounds__(256) void quant_kernel(
    const float* __restrict__ x, int8_t* __restrict__ q,
    float* __restrict__ sx, int Dm)
{
    int s = blockIdx.x;
    int tid = threadIdx.x;
    __shared__ float sm4[4];
    const float4* xr = (const float4*)(x + (size_t)s * Dm);
    int n4 = Dm >> 2;
    float mx = 0.0f;
    for (int i = tid; i < n4; i += 256) {
        float4 t = xr[i];
        if (GELU) { t.x = gelu_tanh(t.x); t.y = gelu_tanh(t.y); t.z = gelu_tanh(t.z); t.w = gelu_tanh(t.w); }
        mx = fmaxf(mx, fmaxf(fmaxf(fabsf(t.x), fabsf(t.y)), fmaxf(fabsf(t.z), fabsf(t.w))));
    }
    mx = block_max(mx, sm4);
    float sc = fmaxf(mx / 127.0f, 1e-8f);
    if (tid == 0) sx[s] = sc;
    float rs = 1.0f / sc;
    char4* qr = (char4*)(q + (size_t)s * Dm);
    for (int i = tid; i < n4; i += 256) {
        float4 t = xr[i];
        if (GELU) { t.x = gelu_tanh(t.x); t.y = gelu_tanh(t.y); t.z = gelu_tanh(t.z); t.w = gelu_tanh(t.w); }
        char4 qq;
        qq.x = (int8_t)fminf(fmaxf(rintf(t.x * rs), -128.0f), 127.0f);
        qq.y = (int8_t)fminf(fmaxf(rintf(t.y * rs), -128.0f), 127.0f);
        qq.z = (int8_t)fminf(fmaxf(rintf(t.z * rs), -128.0f), 127.0f);
        qq.w = (int8_t)fminf(fmaxf(rintf(t.w * rs), -128.0f), 127.0f);
        qr[i] = qq;
    }
}

// ---------------- int8 GEMM via MFMA ----------------
// out[m,n] = (sum_k qx[m,k]*qw[n,k]) * sx[m] * ws[n] + bias[n] (+ res[m,n])
__global__ __launch_bounds__(256) void gemm_w8a8_mfma(
    const int8_t* __restrict__ qx, const float* __restrict__ sx,
    const int8_t* __restrict__ qw, const float* __restrict__ ws,
    const float* __restrict__ bias, const float* __restrict__ res,
    float* __restrict__ out, int M, int O, int K)
{
    int lane = threadIdx.x & 63;
    int wv = threadIdx.x >> 6;
    int l15 = lane & 15;
    int quad = lane >> 4;
    int m_base = blockIdx.y * 64 + wv * 16;
    int n_base = blockIdx.x * 64;

    int ar = m_base + l15; if (ar >= M) ar = M - 1;
    const int8_t* ap = qx + (size_t)ar * K + quad * 16;
    const int8_t* bp = qw + (size_t)(n_base + l15) * K + quad * 16;
    size_t rowK16 = (size_t)16 * K;

    v4i acc0 = {0, 0, 0, 0}, acc1 = {0, 0, 0, 0}, acc2 = {0, 0, 0, 0}, acc3 = {0, 0, 0, 0};
    int nsteps = K >> 6;
    for (int s = 0; s < nsteps; s++) {
        v4i a  = *(const v4i*)(ap + s * 64);
        v4i b0 = *(const v4i*)(bp + s * 64);
        v4i b1 = *(const v4i*)(bp + rowK16 + s * 64);
        v4i b2 = *(const v4i*)(bp + 2 * rowK16 + s * 64);
        v4i b3 = *(const v4i*)(bp + 3 * rowK16 + s * 64);
        acc0 = __builtin_amdgcn_mfma_i32_16x16x64_i8(a, b0, acc0, 0, 0, 0);
        acc1 = __builtin_amdgcn_mfma_i32_16x16x64_i8(a, b1, acc1, 0, 0, 0);
        acc2 = __builtin_amdgcn_mfma_i32_16x16x64_i8(a, b2, acc2, 0, 0, 0);
        acc3 = __builtin_amdgcn_mfma_i32_16x16x64_i8(a, b3, acc3, 0, 0, 0);
    }

    float sxv[4];
    #pragma unroll
    for (int r = 0; r < 4; r++) {
        int m = m_base + quad * 4 + r;
        sxv[r] = (m < M) ? sx[m] : 0.0f;
    }
    v4i accs[4] = {acc0, acc1, acc2, acc3};
    #pragma unroll
    for (int nb = 0; nb < 4; nb++) {
        int n = n_base + nb * 16 + l15;
        float wn = ws[n];
        float bn = bias[n];
        #pragma unroll
        for (int r = 0; r < 4; r++) {
            int m = m_base + quad * 4 + r;
            if (m < M) {
                float y = (float)accs[nb][r] * sxv[r] * wn + bn;
                if (res) y += res[(size_t)m * O + n];
                out[(size_t)m * O + n] = y;
            }
        }
    }
}

// ---------------- attention: tiled flash-style, f32 ----------------
// grid (24 q-tiles, 20 heads), 256 threads.
// Thread (tx=tid&15, ty=tid>>4): queries q0=4*ty.., keys/dims 4*tx..
// qkv layout [S][3840] with q|k|v each [H][64]
__global__ __launch_bounds__(256) void attn_tiled_kernel(
    const float* __restrict__ qkv, float* __restrict__ ao)
{
    __shared__ float Qs[64][68];
    __shared__ float KV[64][68];   // K-tile as [d][k], then V-tile as [k][d]
    __shared__ float Ps[64][68];
    int h = blockIdx.y;
    int q_tile = blockIdx.x;
    int tid = threadIdx.x;
    int tx = tid & 15, ty = tid >> 4;
    int q0 = ty * 4;   // tile-local query base
    int d0 = tx * 4;   // dim base (for PV/output)

    // load Q tile: 64 rows x 64 dims (rows clamped; OOB rows never stored)
    {
        int r = tid >> 2;
        int dq = (tid & 3) * 16;
        int qg = q_tile * 64 + r;
        int qc = qg < S_LEN ? qg : S_LEN - 1;
        const float4* src = (const float4*)(qkv + (size_t)qc * 3840 + h * 64 + dq);
        #pragma unroll
        for (int i = 0; i < 4; i++)
            *(float4*)&Qs[r][dq + i * 4] = src[i];
    }

    float O[4][4] = {};
    float m_run[4], l_run[4];
    #pragma unroll
    for (int i = 0; i < 4; i++) { m_run[i] = -INFINITY; l_run[i] = 0.0f; }

    for (int kt = 0; kt < 24; kt++) {
        int kbase = kt * 64;
        int krem = S_LEN - kbase;  // valid keys in this tile (>=28)

        __syncthreads();  // prev PV done reading KV/Ps (also covers Q-load on kt==0)
        // load K tile transposed: KV[d][k]
        {
            int kk = tid >> 2;
            int dq = (tid & 3) * 16;
            int kg = kbase + kk;
            int kc = kg < S_LEN ? kg : S_LEN - 1;
            const float4* src = (const float4*)(qkv + (size_t)kc * 3840 + 1280 + h * 64 + dq);
            #pragma unroll
            for (int i = 0; i < 4; i++) {
                float4 v = src[i];
                KV[dq + i * 4 + 0][kk] = v.x;
                KV[dq + i * 4 + 1][kk] = v.y;
                KV[dq + i * 4 + 2][kk] = v.z;
                KV[dq + i * 4 + 3][kk] = v.w;
            }
        }
        __syncthreads();

        // scores: s[i][j] = Q[q0+i] . K[k0loc+j]
        float s[4][4] = {};
        int k0loc = tx * 4;
        for (int d = 0; d < 64; d += 4) {
            float4 qv[4], kv[4];
            #pragma unroll
            for (int i = 0; i < 4; i++) qv[i] = *(const float4*)&Qs[q0 + i][d];
            #pragma unroll
            for (int dd = 0; dd < 4; dd++) kv[dd] = *(const float4*)&KV[d + dd][k0loc];
            #pragma unroll
            for (int i = 0; i < 4; i++) {
                float qa[4] = {qv[i].x, qv[i].y, qv[i].z, qv[i].w};
                #pragma unroll
                for (int dd = 0; dd < 4; dd++) {
                    float kb[4] = {kv[dd].x, kv[dd].y, kv[dd].z, kv[dd].w};
                    #pragma unroll
                    for (int j = 0; j < 4; j++)
                        s[i][j] += qa[dd] * kb[j];
                }
            }
        }

        // scale + mask
        #pragma unroll
        for (int i = 0; i < 4; i++)
            #pragma unroll
            for (int j = 0; j < 4; j++) {
                s[i][j] *= 0.125f;
                if (k0loc + j >= krem) s[i][j] = -INFINITY;
            }

        // online softmax per query row (butterfly over the 16 tx lanes)
        #pragma unroll
        for (int i = 0; i < 4; i++) {
            float t = fmaxf(fmaxf(s[i][0], s[i][1]), fmaxf(s[i][2], s[i][3]));
            #pragma unroll
            for (int msk = 1; msk < 16; msk <<= 1)
                t = fmaxf(t, __shfl_xor(t, msk, 64));
            float mn = fmaxf(m_run[i], t);
            float alpha = __expf(m_run[i] - mn);
            m_run[i] = mn;
            float rs = 0.0f;
            #pragma unroll
            for (int j = 0; j < 4; j++) {
                float p = __expf(s[i][j] - mn);
                s[i][j] = p;
                rs += p;
            }
            #pragma unroll
            for (int msk = 1; msk < 16; msk <<= 1)
                rs += __shfl_xor(rs, msk, 64);
            l_run[i] = l_run[i] * alpha + rs;
            #pragma unroll
            for (int j = 0; j < 4; j++) O[i][j] *= alpha;
            *(float4*)&Ps[q0 + i][k0loc] = *(float4*)&s[i][0];
        }
        __syncthreads();  // S-stage reads of KV done; Ps visible

        // load V tile: KV[k][d]
        {
            int kk = tid >> 2;
            int dq = (tid & 3) * 16;
            int kg = kbase + kk;
            int kc = kg < S_LEN ? kg : S_LEN - 1;
            const float4* src = (const float4*)(qkv + (size_t)kc * 3840 + 2560 + h * 64 + dq);
            #pragma unroll
            for (int i = 0; i < 4; i++)
                *(float4*)&KV[kk][dq + i * 4] = src[i];
        }
        __syncthreads();

        // PV: O[i][j] += sum_k Ps[q0+i][k] * V[k][d0+j]
        for (int kb = 0; kb < 64; kb += 4) {
            float4 pv[4], vv[4];
            #pragma unroll
            for (int i = 0; i < 4; i++) pv[i] = *(const float4*)&Ps[q0 + i][kb];
            #pragma unroll
            for (int kk = 0; kk < 4; kk++) vv[kk] = *(const float4*)&KV[kb + kk][d0];
            #pragma unroll
            for (int i = 0; i < 4; i++) {
                float pa[4] = {pv[i].x, pv[i].y, pv[i].z, pv[i].w};
                #pragma unroll
                for (int kk = 0; kk < 4; kk++) {
                    float vb[4] = {vv[kk].x, vv[kk].y, vv[kk].z, vv[kk].w};
                    #pragma unroll
                    for (int j = 0; j < 4; j++)
                        O[i][j] += pa[kk] * vb[j];
                }
            }
        }
    }

    // epilogue
    #pragma unroll
    for (int i = 0; i < 4; i++) {
        int qg = q_tile * 64 + q0 + i;
        if (qg < S_LEN) {
            float rl = 1.0f / l_run[i];
            float4 o;
            o.x = O[i][0] * rl; o.y = O[i][1] * rl; o.z = O[i][2] * rl; o.w = O[i][3] * rl;
            *(float4*)(ao + (size_t)qg * D_MODEL + h * 64 + d0) = o;
        }
    }
}

// ---------------- final pool + layernorm ----------------
__global__ __launch_bounds__(256) void pool_ln_kernel(
    const float* __restrict__ h, const float* __restrict__ w,
    const float* __restrict__ b, float* __restrict__ out)
{
    int t = blockIdx.x;
    int tid = threadIdx.x;
    __shared__ float sm4[4];
    const float* r0 = h + (size_t)(2 * t) * D_MODEL;
    const float* r1 = r0 + D_MODEL;
    float v[5];
    float s1 = 0.0f;
    for (int i = 0; i < 5; i++) {
        int idx = tid + 256 * i;
        float x = 0.5f * (r0[idx] + r1[idx]);
        v[i] = x;
        s1 += x;
    }
    float mu = block_sum(s1, sm4) * (1.0f / 1280.0f);
    float s2 = 0.0f;
    for (int i = 0; i < 5; i++) {
        float d = v[i] - mu;
        s2 += d * d;
    }
    float var = block_sum(s2, sm4) * (1.0f / 1280.0f);
    float inv = rsqrtf(var + 1e-5f);
    for (int i = 0; i < 5; i++) {
        int idx = tid + 256 * i;
        out[(size_t)t * D_MODEL + idx] = (v[i] - mu) * inv * w[idx] + b[idx];
    }
}

// ---------------- host ----------------

static inline size_t al256(size_t x) { return (x + 255) & ~(size_t)255; }

extern "C" void kernel_launch(void* const* d_in, const int* in_sizes, int n_in,
                              void* d_out, int out_size, void* d_ws, size_t ws_size,
                              hipStream_t stream) {
    const float* in_feat = (const float*)d_in[0];   // [1][128][3000]
    const float* conv1_w = (const float*)d_in[1];
    const float* conv1_b = (const float*)d_in[2];
    const float* conv2_w = (const float*)d_in[3];
    const float* conv2_b = (const float*)d_in[4];
    const float* pos_emb = (const float*)d_in[5];
    const float* ln1_w   = (const float*)d_in[6];
    const float* ln1_b   = (const float*)d_in[7];
    const float* qkv_w   = (const float*)d_in[8];
    const float* qkv_b   = (const float*)d_in[9];
    const float* out_w   = (const float*)d_in[10];
    const float* out_b   = (const float*)d_in[11];
    const float* ln2_w   = (const float*)d_in[12];
    const float* ln2_b   = (const float*)d_in[13];
    const float* fc1_w   = (const float*)d_in[14];
    const float* fc1_b   = (const float*)d_in[15];
    const float* fc2_w   = (const float*)d_in[16];
    const float* fc2_b   = (const float*)d_in[17];
    const float* lnf_w   = (const float*)d_in[18];
    const float* lnf_b   = (const float*)d_in[19];
    float* outp = (float*)d_out;

    char* ws = (char*)d_ws;
    size_t off = 0;
    auto carve = [&](size_t bytes) {
        void* p = ws + off;
        off += al256(bytes);
        return p;
    };
    float*  hA      = (float*)carve((size_t)S_LEN * D_MODEL * 4);
    float*  hB      = (float*)carve((size_t)S_LEN * D_MODEL * 4);
    float*  qkvbuf  = (float*)carve((size_t)S_LEN * 3840 * 4);       // also g1 / W2r
    float*  aobuf   = (float*)carve((size_t)S_LEN * D_MODEL * 4);    // also W1r
    float*  f1buf   = (float*)carve((size_t)S_LEN * FF_DIM * 4);     // also A2
    int8_t* q8      = (int8_t*)carve((size_t)S_LEN * FF_DIM);        // also A1
    float*  sx      = (float*)carve((size_t)S_LEN * 4);
    int8_t* qw_qkv  = (int8_t*)carve((size_t)3840 * 1280);
    float*  ws_qkv  = (float*)carve((size_t)3840 * 4);
    int8_t* qw_out  = (int8_t*)carve((size_t)1280 * 1280);
    float*  ws_out  = (float*)carve((size_t)1280 * 4);
    int8_t* qw_fc1  = (int8_t*)carve((size_t)5120 * 1280);
    float*  ws_fc1  = (float*)carve((size_t)5120 * 4);
    int8_t* qw_fc2  = (int8_t*)carve((size_t)1280 * 5120);
    float*  ws_fc2  = (float*)carve((size_t)1280 * 4);
    (void)ws_size; (void)n_in; (void)in_sizes; (void)out_size;

    // conv stem aliases (all consumed before the transformer loop starts)
    // hi/lo bf16 planes occupy exactly the bytes the old f32 buffers used.
    unsigned short* A1h = (unsigned short*)q8;            // 3000*384*2*2 = 4.6 MB  <= 7.68 MB
    unsigned short* A1l = A1h + (size_t)3000 * 384;
    unsigned short* W1h = (unsigned short*)aobuf;         // 1280*384*2*2 = 2.0 MB  <= 7.68 MB
    unsigned short* W1l = W1h + (size_t)1280 * 384;
    float* g1 = qkvbuf;                                   // 3000*1280*4 = 15.4 MB <= 23 MB
    unsigned short* A2h = (unsigned short*)f1buf;         // 1500*3840*2*2 = 23 MB <= 30.7 MB
    unsigned short* A2l = A2h + (size_t)1500 * 3840;
    unsigned short* W2h = (unsigned short*)qkvbuf;        // 1280*3840*2*2 = 19.7 MB <= 23 MB (after g1 consumed)
    unsigned short* W2l = W2h + (size_t)1280 * 3840;

    // conv1: im2col (K=384) + bf16x3 MFMA GEMM + gelu -> g1[3000][1280]
    im2col1_kernel<<<dim3(12, 384), 256, 0, stream>>>(in_feat, A1h, A1l);
    wreorder_kernel<<<1280, 256, 0, stream>>>(conv1_w, W1h, W1l, 128);
    gemm_bf16x3_kernel<0><<<dim3(20, 47), 256, 0, stream>>>(A1h, A1l, W1h, W1l, conv1_b, nullptr, g1, 3000, 1280, 384);
    // conv2: im2col (row concat, K=3840) + bf16x3 MFMA GEMM + gelu + pos -> hA[1500][1280]
    im2col2_kernel<<<dim3(15, 1500), 256, 0, stream>>>(g1, A2h, A2l);
    wreorder_kernel<<<1280, 256, 0, stream>>>(conv2_w, W2h, W2l, 1280);
    gemm_bf16x3_kernel<1><<<dim3(20, 24), 256, 0, stream>>>(A2h, A2l, W2h, W2l, conv2_b, pos_emb, hA, 1500, 1280, 3840);

    float* h = hA;
    float* hn = hB;
    const int mtiles = (S_LEN + 63) / 64;  // 24

    for (int l = 0; l < N_LAYER; l++) {
        // quantize this layer's weights
        wquant_kernel<<<3840, 256, 0, stream>>>(qkv_w + (size_t)l * 3840 * 1280, qw_qkv, ws_qkv, 1280);
        wquant_kernel<<<1280, 256, 0, stream>>>(out_w + (size_t)l * 1280 * 1280, qw_out, ws_out, 1280);
        wquant_kernel<<<5120, 256, 0, stream>>>(fc1_w + (size_t)l * 5120 * 1280, qw_fc1, ws_fc1, 1280);
        wquant_kernel<<<1280, 256, 0, stream>>>(fc2_w + (size_t)l * 1280 * 5120, qw_fc2, ws_fc2, 5120);

        // attention block
        rmsnorm_quant_kernel<<<S_LEN, 256, 0, stream>>>(h, ln1_w + l * D_MODEL, ln1_b + l * D_MODEL, q8, sx);
        gemm_w8a8_mfma<<<dim3(60, mtiles), 256, 0, stream>>>(q8, sx, qw_qkv, ws_qkv,
            qkv_b + (size_t)l * 3840, nullptr, qkvbuf, S_LEN, 3840, 1280);
        attn_tiled_kernel<<<dim3(24, N_HEAD), 256, 0, stream>>>(qkvbuf, aobuf);
        quant_kernel<false><<<S_LEN, 256, 0, stream>>>(aobuf, q8, sx, D_MODEL);
        gemm_w8a8_mfma<<<dim3(20, mtiles), 256, 0, stream>>>(q8, sx, qw_out, ws_out,
            out_b + (size_t)l * 1280, h, hn, S_LEN, 1280, 1280);
        { float* t = h; h = hn; hn = t; }

        // MLP block
        rmsnorm_quant_kernel<<<S_LEN, 256, 0, stream>>>(h, ln2_w + l * D_MODEL, ln2_b + l * D_MODEL, q8, sx);
        gemm_w8a8_mfma<<<dim3(80, mtiles), 256, 0, stream>>>(q8, sx, qw_fc1, ws_fc1,
            fc1_b + (size_t)l * 5120, nullptr, f1buf, S_LEN, 5120, 1280);
        quant_kernel<true><<<S_LEN, 256, 0, stream>>>(f1buf, q8, sx, FF_DIM);
        gemm_w8a8_mfma<<<dim3(20, mtiles), 256, 0, stream>>>(q8, sx, qw_fc2, ws_fc2,
            fc2_b + (size_t)l * 1280, h, hn, S_LEN, 1280, 5120);
        { float* t = h; h = hn; hn = t; }
    }

    pool_ln_kernel<<<750, 256, 0, stream>>>(h, lnf_w, lnf_b, outp);
}

// Round 2
// 2631.511 us; speedup vs baseline: 1.0676x; 1.0676x over previous
//
#include <hip/hip_runtime.h>
#include <stdint.h>

#define S_LEN 1500
#define D_MODEL 1280
#define N_HEAD 20
#define D_HEAD 64
#define FF_DIM 5120
#define N_LAYER 4

typedef int v4i __attribute__((ext_vector_type(4)));
typedef short v8s __attribute__((ext_vector_type(8)));
typedef float v4f __attribute__((ext_vector_type(4)));

// ---------------- helpers ----------------

__device__ inline float gelu_tanh(float x) {
    // jax.nn.gelu default (approximate=True)
    float x3 = x * x * x;
    return 0.5f * x * (1.0f + tanhf(0.7978845608028654f * (x + 0.044715f * x3)));
}

__device__ inline float wred_sum(float v) {
    for (int o = 32; o > 0; o >>= 1) v += __shfl_down(v, o, 64);
    return v;
}
__device__ inline float wred_max(float v) {
    for (int o = 32; o > 0; o >>= 1) v = fmaxf(v, __shfl_down(v, o, 64));
    return v;
}
// blockDim.x == 256 (4 waves) assumed
__device__ inline float block_sum(float v, float* sm4) {
    v = wred_sum(v);
    int w = threadIdx.x >> 6;
    if ((threadIdx.x & 63) == 0) sm4[w] = v;
    __syncthreads();
    float r = sm4[0] + sm4[1] + sm4[2] + sm4[3];
    __syncthreads();
    return r;
}
__device__ inline float block_max(float v, float* sm4) {
    v = wred_max(v);
    int w = threadIdx.x >> 6;
    if ((threadIdx.x & 63) == 0) sm4[w] = v;
    __syncthreads();
    float r = fmaxf(fmaxf(sm4[0], sm4[1]), fmaxf(sm4[2], sm4[3]));
    __syncthreads();
    return r;
}

// f32 -> bf16 round-to-nearest-even, and back
__device__ inline unsigned short f2bf(float x) {
    unsigned int u = __float_as_uint(x);
    u += 0x7fffu + ((u >> 16) & 1u);
    return (unsigned short)(u >> 16);
}
__device__ inline float bf2f(unsigned short h) {
    return __uint_as_float(((unsigned int)h) << 16);
}

// async global->LDS, 16B per lane (wave-uniform LDS base + lane*16)
__device__ inline void gload_lds16(const void* g, void* l) {
    __builtin_amdgcn_global_load_lds(
        (const __attribute__((address_space(1))) char*)g,
        (__attribute__((address_space(3))) char*)l, 16, 0, 0);
}

// ---------------- conv stem: im2col + split-bf16 MFMA GEMM ----------------
// f32 operands are split x = hi + lo (both bf16, RNE). GEMM computes
// Ah*Bh + Al*Bh + Ah*Bl on the bf16 matrix cores with f32 accumulation;
// residual error ~2^-18 relative (f32-equivalent accuracy).

// A1[t][tap*128+i] = in[i][t-1+tap], t in [0,3000)  (hi/lo bf16 planes)
__global__ __launch_bounds__(256) void im2col1_kernel(
    const float* __restrict__ x, unsigned short* __restrict__ Ah,
    unsigned short* __restrict__ Al)
{
    int t = blockIdx.x * 256 + threadIdx.x;
    int col = blockIdx.y;  // 0..383
    if (t >= 3000) return;
    int tap = col >> 7, i = col & 127;
    int src = t - 1 + tap;
    float v = (src >= 0 && src < 3000) ? x[(size_t)i * 3000 + src] : 0.0f;
    unsigned short h = f2bf(v);
    Ah[(size_t)t * 384 + col] = h;
    Al[(size_t)t * 384 + col] = f2bf(v - bf2f(h));
}

// A2[t][tap*1280+o] = g1[2t-1+tap][o], t in [0,1500)  (hi/lo bf16 planes)
__global__ __launch_bounds__(256) void im2col2_kernel(
    const float* __restrict__ g1, unsigned short* __restrict__ Ah,
    unsigned short* __restrict__ Al)
{
    int col = blockIdx.x * 256 + threadIdx.x;  // 0..3839
    int t = blockIdx.y;
    if (col >= 3840) return;
    int tap = col / 1280, o = col - tap * 1280;
    int src = 2 * t - 1 + tap;
    float v = (src >= 0 && src < 3000) ? g1[(size_t)src * 1280 + o] : 0.0f;
    unsigned short h = f2bf(v);
    Ah[(size_t)t * 3840 + col] = h;
    Al[(size_t)t * 3840 + col] = f2bf(v - bf2f(h));
}

// out[o][tap*C+i] = w[o][i][tap]  (hi/lo bf16 planes)
__global__ __launch_bounds__(256) void wreorder_kernel(
    const float* __restrict__ w, unsigned short* __restrict__ woh,
    unsigned short* __restrict__ wol, int C)
{
    int o = blockIdx.x;
    int KC = 3 * C;
    const float* wr = w + (size_t)o * KC;
    for (int col = threadIdx.x; col < KC; col += 256) {
        int tap = col / C, i = col - tap * C;
        float v = wr[i * 3 + tap];
        unsigned short h = f2bf(v);
        woh[(size_t)o * KC + col] = h;
        wol[(size_t)o * KC + col] = f2bf(v - bf2f(h));
    }
}

// C[m][n] = gelu(A[m,:].W[n,:] + bias[n]) (+ pos[m][n] if EPI==1)
// 128x128 tile, 4 waves (2x2, each 64x64), LDS double-buffered via
// global_load_lds width=16 (m97 structure), XCD-swizzled flat grid.
// Planes staged per buffer: 0=Ah 1=Al 2=Bh 3=Bl, each [128][32] bf16.
template <int EPI>
__global__ __launch_bounds__(256, 2) void gemm_conv_bf16x3(
    const unsigned short* __restrict__ Ah, const unsigned short* __restrict__ Al,
    const unsigned short* __restrict__ Wh, const unsigned short* __restrict__ Wl,
    const float* __restrict__ bias, const float* __restrict__ pos,
    float* __restrict__ out, int M, int N, int K, int nTilesN)
{
    __shared__ unsigned short lds[2][4][128][32];   // 64 KB
    int tid = threadIdx.x;
    int lane = tid & 63;
    int wv = tid >> 6;
    int l15 = lane & 15, quad = lane >> 4;
    int wm = wv >> 1, wn = wv & 1;   // 2x2 wave grid

    // bijective XCD swizzle (gridDim.x % 8 == 0)
    int nwg = gridDim.x;
    int cpx = nwg >> 3;
    int bid = blockIdx.x;
    int swz = (bid & 7) * cpx + (bid >> 3);
    int bx = swz % nTilesN, by = swz / nTilesN;
    int m0 = by * 128, n0 = bx * 128;

    // wave wv stages plane wv: 8 chunks x 1024B; lane -> row (lane>>2), 16B slot (lane&3)
    const unsigned short* splane = (wv == 0) ? Ah : (wv == 1) ? Al : (wv == 2) ? Wh : Wl;
    int rbase = (wv < 2) ? m0 : n0;
    int rlim  = (wv < 2) ? M : N;
    const unsigned short* srcp[8];
    #pragma unroll
    for (int c = 0; c < 8; c++) {
        int row = rbase + c * 16 + (lane >> 2);
        if (row >= rlim) row = rlim - 1;
        srcp[c] = splane + (size_t)row * K + (lane & 3) * 8;
    }

    auto stage = [&](int nb, int k0) {
        char* lbase = (char*)&lds[nb][wv][0][0];
        #pragma unroll
        for (int c = 0; c < 8; c++)
            gload_lds16(srcp[c] + k0, lbase + c * 1024);
    };

    v4f acc[4][4];
    #pragma unroll
    for (int i = 0; i < 4; i++)
        #pragma unroll
        for (int j = 0; j < 4; j++) acc[i][j] = (v4f){0.0f, 0.0f, 0.0f, 0.0f};

    int nsteps = K >> 5;
    stage(0, 0);
    __syncthreads();   // buf0 staged (vmcnt drain at barrier)
    int cur = 0;
    for (int t = 0; t < nsteps; t++) {
        if (t + 1 < nsteps) stage(cur ^ 1, (t + 1) * 32);   // prefetch next (hidden under MFMA)
        v8s ah[4], al2[4], bh[4], bl[4];
        #pragma unroll
        for (int i = 0; i < 4; i++) {
            ah[i]  = *(const v8s*)&lds[cur][0][wm * 64 + i * 16 + l15][quad * 8];
            al2[i] = *(const v8s*)&lds[cur][1][wm * 64 + i * 16 + l15][quad * 8];
            bh[i]  = *(const v8s*)&lds[cur][2][wn * 64 + i * 16 + l15][quad * 8];
            bl[i]  = *(const v8s*)&lds[cur][3][wn * 64 + i * 16 + l15][quad * 8];
        }
        #pragma unroll
        for (int i = 0; i < 4; i++)
            #pragma unroll
            for (int j = 0; j < 4; j++) {
                acc[i][j] = __builtin_amdgcn_mfma_f32_16x16x32_bf16(ah[i],  bh[j], acc[i][j], 0, 0, 0);
                acc[i][j] = __builtin_amdgcn_mfma_f32_16x16x32_bf16(al2[i], bh[j], acc[i][j], 0, 0, 0);
                acc[i][j] = __builtin_amdgcn_mfma_f32_16x16x32_bf16(ah[i],  bl[j], acc[i][j], 0, 0, 0);
            }
        __syncthreads();   // drains prefetch + all reads of lds[cur] done
        cur ^= 1;
    }

    #pragma unroll
    for (int i = 0; i < 4; i++) {
        #pragma unroll
        for (int j = 0; j < 4; j++) {
            int n = n0 + wn * 64 + j * 16 + l15;
            float bn = bias[n];
            #pragma unroll
            for (int r = 0; r < 4; r++) {
                int m = m0 + wm * 64 + i * 16 + quad * 4 + r;
                if (m < M) {
                    float v = gelu_tanh(acc[i][j][r] + bn);
                    if (EPI == 1) v += pos[(size_t)m * N + n];
                    out[(size_t)m * N + n] = v;
                }
            }
        }
    }
}

// ---------------- quantization kernels ----------------

// per-row weight quant: block per row, float4
__global__ __launch_bounds__(256) void wquant_kernel(
    const float* __restrict__ w, int8_t* __restrict__ qw,
    float* __restrict__ ws, int K)
{
    int r = blockIdx.x;
    int tid = threadIdx.x;
    __shared__ float sm4[4];
    const float4* wr = (const float4*)(w + (size_t)r * K);
    int n4 = K >> 2;
    float mx = 0.0f;
    for (int i = tid; i < n4; i += 256) {
        float4 v = wr[i];
        mx = fmaxf(mx, fmaxf(fmaxf(fabsf(v.x), fabsf(v.y)), fmaxf(fabsf(v.z), fabsf(v.w))));
    }
    mx = block_max(mx, sm4);
    float sc = fmaxf(mx / 127.0f, 1e-8f);
    if (tid == 0) ws[r] = sc;
    float rs = 1.0f / sc;
    char4* qr = (char4*)(qw + (size_t)r * K);
    for (int i = tid; i < n4; i += 256) {
        float4 v = wr[i];
        char4 q;
        q.x = (int8_t)fminf(fmaxf(rintf(v.x * rs), -128.0f), 127.0f);
        q.y = (int8_t)fminf(fmaxf(rintf(v.y * rs), -128.0f), 127.0f);
        q.z = (int8_t)fminf(fmaxf(rintf(v.z * rs), -128.0f), 127.0f);
        q.w = (int8_t)fminf(fmaxf(rintf(v.w * rs), -128.0f), 127.0f);
        qr[i] = q;
    }
}

// RMSNorm + per-token quant, D=1280, block per token
__global__ __launch_bounds__(256) void rmsnorm_quant_kernel(
    const float* __restrict__ x, const float* __restrict__ w,
    const float* __restrict__ b, int8_t* __restrict__ q,
    float* __restrict__ sx)
{
    int s = blockIdx.x;
    int tid = threadIdx.x;
    __shared__ float sm4[4];
    const float* xr = x + (size_t)s * D_MODEL;
    float v[5];
    float ss = 0.0f;
    for (int i = 0; i < 5; i++) {
        float t = xr[tid + 256 * i];
        v[i] = t;
        ss += t * t;
    }
    ss = block_sum(ss, sm4);
    float inv = rsqrtf(ss * (1.0f / 1280.0f) + 1e-6f);
    float mx = 0.0f;
    for (int i = 0; i < 5; i++) {
        int idx = tid + 256 * i;
        float t = v[i] * inv * w[idx] + b[idx];
        v[i] = t;
        mx = fmaxf(mx, fabsf(t));
    }
    mx = block_max(mx, sm4);
    float sc = fmaxf(mx / 127.0f, 1e-8f);
    if (tid == 0) sx[s] = sc;
    float rs = 1.0f / sc;
    for (int i = 0; i < 5; i++) {
        float qv = rintf(v[i] * rs);
        qv = fminf(fmaxf(qv, -128.0f), 127.0f);
        q[(size_t)s * D_MODEL + tid + 256 * i] = (int8_t)qv;
    }
}

// per-token quant (optionally fused gelu); block per token
template <bool GELU>
__global__ __launch_bounds__(256) void quant_kernel(
    const float* __restrict__ x, int8_t* __restrict__ q,
    float* __restrict__ sx, int Dm)
{
    int s = blockIdx.x;
    int tid = threadIdx.x;
    __shared__ float sm4[4];
    const float4* xr = (const float4*)(x + (size_t)s * Dm);
    int n4 = Dm >> 2;
    float mx = 0.0f;
    for (int i = tid; i < n4; i += 256) {
        float4 t = xr[i];
        if (GELU) { t.x = gelu_tanh(t.x); t.y = gelu_tanh(t.y); t.z = gelu_tanh(t.z); t.w = gelu_tanh(t.w); }
        mx = fmaxf(mx, fmaxf(fmaxf(fabsf(t.x), fabsf(t.y)), fmaxf(fabsf(t.z), fabsf(t.w))));
    }
    mx = block_max(mx, sm4);
    float sc = fmaxf(mx / 127.0f, 1e-8f);
    if (tid == 0) sx[s] = sc;
    float rs = 1.0f / sc;
    char4* qr = (char4*)(q + (size_t)s * Dm);
    for (int i = tid; i < n4; i += 256) {
        float4 t = xr[i];
        if (GELU) { t.x = gelu_tanh(t.x); t.y = gelu_tanh(t.y); t.z = gelu_tanh(t.z); t.w = gelu_tanh(t.w); }
        char4 qq;
        qq.x = (int8_t)fminf(fmaxf(rintf(t.x * rs), -128.0f), 127.0f);
        qq.y = (int8_t)fminf(fmaxf(rintf(t.y * rs), -128.0f), 127.0f);
        qq.z = (int8_t)fminf(fmaxf(rintf(t.z * rs), -128.0f), 127.0f);
        qq.w = (int8_t)fminf(fmaxf(rintf(t.w * rs), -128.0f), 127.0f);
        qr[i] = qq;
    }
}

// ---------------- int8 GEMM via MFMA ----------------
// out[m,n] = (sum_k qx[m,k]*qw[n,k]) * sx[m] * ws[n] + bias[n] (+ res[m,n])
__global__ __launch_bounds__(256) void gemm_w8a8_mfma(
    const int8_t* __restrict__ qx, const float* __restrict__ sx,
    const int8_t* __restrict__ qw, const float* __restrict__ ws,
    const float* __restrict__ bias, const float* __restrict__ res,
    float* __restrict__ out, int M, int O, int K)
{
    int lane = threadIdx.x & 63;
    int wv = threadIdx.x >> 6;
    int l15 = lane & 15;
    int quad = lane >> 4;
    int m_base = blockIdx.y * 64 + wv * 16;
    int n_base = blockIdx.x * 64;

    int ar = m_base + l15; if (ar >= M) ar = M - 1;
    const int8_t* ap = qx + (size_t)ar * K + quad * 16;
    const int8_t* bp = qw + (size_t)(n_base + l15) * K + quad * 16;
    size_t rowK16 = (size_t)16 * K;

    v4i acc0 = {0, 0, 0, 0}, acc1 = {0, 0, 0, 0}, acc2 = {0, 0, 0, 0}, acc3 = {0, 0, 0, 0};
    int nsteps = K >> 6;
    for (int s = 0; s < nsteps; s++) {
        v4i a  = *(const v4i*)(ap + s * 64);
        v4i b0 = *(const v4i*)(bp + s * 64);
        v4i b1 = *(const v4i*)(bp + rowK16 + s * 64);
        v4i b2 = *(const v4i*)(bp + 2 * rowK16 + s * 64);
        v4i b3 = *(const v4i*)(bp + 3 * rowK16 + s * 64);
        acc0 = __builtin_amdgcn_mfma_i32_16x16x64_i8(a, b0, acc0, 0, 0, 0);
        acc1 = __builtin_amdgcn_mfma_i32_16x16x64_i8(a, b1, acc1, 0, 0, 0);
        acc2 = __builtin_amdgcn_mfma_i32_16x16x64_i8(a, b2, acc2, 0, 0, 0);
        acc3 = __builtin_amdgcn_mfma_i32_16x16x64_i8(a, b3, acc3, 0, 0, 0);
    }

    float sxv[4];
    #pragma unroll
    for (int r = 0; r < 4; r++) {
        int m = m_base + quad * 4 + r;
        sxv[r] = (m < M) ? sx[m] : 0.0f;
    }
    v4i accs[4] = {acc0, acc1, acc2, acc3};
    #pragma unroll
    for (int nb = 0; nb < 4; nb++) {
        int n = n_base + nb * 16 + l15;
        float wn = ws[n];
        float bn = bias[n];
        #pragma unroll
        for (int r = 0; r < 4; r++) {
            int m = m_base + quad * 4 + r;
            if (m < M) {
                float y = (float)accs[nb][r] * sxv[r] * wn + bn;
                if (res) y += res[(size_t)m * O + n];
                out[(size_t)m * O + n] = y;
            }
        }
    }
}

// ---------------- attention: tiled flash-style, f32 ----------------
// grid (24 q-tiles, 20 heads), 256 threads.
// Thread (tx=tid&15, ty=tid>>4): queries q0=4*ty.., keys/dims 4*tx..
// qkv layout [S][3840] with q|k|v each [H][64]
__global__ __launch_bounds__(256) void attn_tiled_kernel(
    const float* __restrict__ qkv, float* __restrict__ ao)
{
    __shared__ float Qs[64][68];
    __shared__ float KV[64][68];   // K-tile as [d][k], then V-tile as [k][d]
    __shared__ float Ps[64][68];
    int h = blockIdx.y;
    int q_tile = blockIdx.x;
    int tid = threadIdx.x;
    int tx = tid & 15, ty = tid >> 4;
    int q0 = ty * 4;   // tile-local query base
    int d0 = tx * 4;   // dim base (for PV/output)

    // load Q tile: 64 rows x 64 dims (rows clamped; OOB rows never stored)
    {
        int r = tid >> 2;
        int dq = (tid & 3) * 16;
        int qg = q_tile * 64 + r;
        int qc = qg < S_LEN ? qg : S_LEN - 1;
        const float4* src = (const float4*)(qkv + (size_t)qc * 3840 + h * 64 + dq);
        #pragma unroll
        for (int i = 0; i < 4; i++)
            *(float4*)&Qs[r][dq + i * 4] = src[i];
    }

    float O[4][4] = {};
    float m_run[4], l_run[4];
    #pragma unroll
    for (int i = 0; i < 4; i++) { m_run[i] = -INFINITY; l_run[i] = 0.0f; }

    for (int kt = 0; kt < 24; kt++) {
        int kbase = kt * 64;
        int krem = S_LEN - kbase;  // valid keys in this tile (>=28)

        __syncthreads();  // prev PV done reading KV/Ps (also covers Q-load on kt==0)
        // load K tile transposed: KV[d][k]
        {
            int kk = tid >> 2;
            int dq = (tid & 3) * 16;
            int kg = kbase + kk;
            int kc = kg < S_LEN ? kg : S_LEN - 1;
            const float4* src = (const float4*)(qkv + (size_t)kc * 3840 + 1280 + h * 64 + dq);
            #pragma unroll
            for (int i = 0; i < 4; i++) {
                float4 v = src[i];
                KV[dq + i * 4 + 0][kk] = v.x;
                KV[dq + i * 4 + 1][kk] = v.y;
                KV[dq + i * 4 + 2][kk] = v.z;
                KV[dq + i * 4 + 3][kk] = v.w;
            }
        }
        __syncthreads();

        // scores: s[i][j] = Q[q0+i] . K[k0loc+j]
        float s[4][4] = {};
        int k0loc = tx * 4;
        for (int d = 0; d < 64; d += 4) {
            float4 qv[4], kv[4];
            #pragma unroll
            for (int i = 0; i < 4; i++) qv[i] = *(const float4*)&Qs[q0 + i][d];
            #pragma unroll
            for (int dd = 0; dd < 4; dd++) kv[dd] = *(const float4*)&KV[d + dd][k0loc];
            #pragma unroll
            for (int i = 0; i < 4; i++) {
                float qa[4] = {qv[i].x, qv[i].y, qv[i].z, qv[i].w};
                #pragma unroll
                for (int dd = 0; dd < 4; dd++) {
                    float kb[4] = {kv[dd].x, kv[dd].y, kv[dd].z, kv[dd].w};
                    #pragma unroll
                    for (int j = 0; j < 4; j++)
                        s[i][j] += qa[dd] * kb[j];
                }
            }
        }

        // scale + mask
        #pragma unroll
        for (int i = 0; i < 4; i++)
            #pragma unroll
            for (int j = 0; j < 4; j++) {
                s[i][j] *= 0.125f;
                if (k0loc + j >= krem) s[i][j] = -INFINITY;
            }

        // online softmax per query row (butterfly over the 16 tx lanes)
        #pragma unroll
        for (int i = 0; i < 4; i++) {
            float t = fmaxf(fmaxf(s[i][0], s[i][1]), fmaxf(s[i][2], s[i][3]));
            #pragma unroll
            for (int msk = 1; msk < 16; msk <<= 1)
                t = fmaxf(t, __shfl_xor(t, msk, 64));
            float mn = fmaxf(m_run[i], t);
            float alpha = __expf(m_run[i] - mn);
            m_run[i] = mn;
            float rs = 0.0f;
            #pragma unroll
            for (int j = 0; j < 4; j++) {
                float p = __expf(s[i][j] - mn);
                s[i][j] = p;
                rs += p;
            }
            #pragma unroll
            for (int msk = 1; msk < 16; msk <<= 1)
                rs += __shfl_xor(rs, msk, 64);
            l_run[i] = l_run[i] * alpha + rs;
            #pragma unroll
            for (int j = 0; j < 4; j++) O[i][j] *= alpha;
            *(float4*)&Ps[q0 + i][k0loc] = *(float4*)&s[i][0];
        }
        __syncthreads();  // S-stage reads of KV done; Ps visible

        // load V tile: KV[k][d]
        {
            int kk = tid >> 2;
            int dq = (tid & 3) * 16;
            int kg = kbase + kk;
            int kc = kg < S_LEN ? kg : S_LEN - 1;
            const float4* src = (const float4*)(qkv + (size_t)kc * 3840 + 2560 + h * 64 + dq);
            #pragma unroll
            for (int i = 0; i < 4; i++)
                *(float4*)&KV[kk][dq + i * 4] = src[i];
        }
        __syncthreads();

        // PV: O[i][j] += sum_k Ps[q0+i][k] * V[k][d0+j]
        for (int kb = 0; kb < 64; kb += 4) {
            float4 pv[4], vv[4];
            #pragma unroll
            for (int i = 0; i < 4; i++) pv[i] = *(const float4*)&Ps[q0 + i][kb];
            #pragma unroll
            for (int kk = 0; kk < 4; kk++) vv[kk] = *(const float4*)&KV[kb + kk][d0];
            #pragma unroll
            for (int i = 0; i < 4; i++) {
                float pa[4] = {pv[i].x, pv[i].y, pv[i].z, pv[i].w};
                #pragma unroll
                for (int kk = 0; kk < 4; kk++) {
                    float vb[4] = {vv[kk].x, vv[kk].y, vv[kk].z, vv[kk].w};
                    #pragma unroll
                    for (int j = 0; j < 4; j++)
                        O[i][j] += pa[kk] * vb[j];
                }
            }
        }
    }

    // epilogue
    #pragma unroll
    for (int i = 0; i < 4; i++) {
        int qg = q_tile * 64 + q0 + i;
        if (qg < S_LEN) {
            float rl = 1.0f / l_run[i];
            float4 o;
            o.x = O[i][0] * rl; o.y = O[i][1] * rl; o.z = O[i][2] * rl; o.w = O[i][3] * rl;
            *(float4*)(ao + (size_t)qg * D_MODEL + h * 64 + d0) = o;
        }
    }
}

// ---------------- final pool + layernorm ----------------
__global__ __launch_bounds__(256) void pool_ln_kernel(
    const float* __restrict__ h, const float* __restrict__ w,
    const float* __restrict__ b, float* __restrict__ out)
{
    int t = blockIdx.x;
    int tid = threadIdx.x;
    __shared__ float sm4[4];
    const float* r0 = h + (size_t)(2 * t) * D_MODEL;
    const float* r1 = r0 + D_MODEL;
    float v[5];
    float s1 = 0.0f;
    for (int i = 0; i < 5; i++) {
        int idx = tid + 256 * i;
        float x = 0.5f * (r0[idx] + r1[idx]);
        v[i] = x;
        s1 += x;
    }
    float mu = block_sum(s1, sm4) * (1.0f / 1280.0f);
    float s2 = 0.0f;
    for (int i = 0; i < 5; i++) {
        float d = v[i] - mu;
        s2 += d * d;
    }
    float var = block_sum(s2, sm4) * (1.0f / 1280.0f);
    float inv = rsqrtf(var + 1e-5f);
    for (int i = 0; i < 5; i++) {
        int idx = tid + 256 * i;
        out[(size_t)t * D_MODEL + idx] = (v[i] - mu) * inv * w[idx] + b[idx];
    }
}

// ---------------- host ----------------

static inline size_t al256(size_t x) { return (x + 255) & ~(size_t)255; }

extern "C" void kernel_launch(void* const* d_in, const int* in_sizes, int n_in,
                              void* d_out, int out_size, void* d_ws, size_t ws_size,
                              hipStream_t stream) {
    const float* in_feat = (const float*)d_in[0];   // [1][128][3000]
    const float* conv1_w = (const float*)d_in[1];
    const float* conv1_b = (const float*)d_in[2];
    const float* conv2_w = (const float*)d_in[3];
    const float* conv2_b = (const float*)d_in[4];
    const float* pos_emb = (const float*)d_in[5];
    const float* ln1_w   = (const float*)d_in[6];
    const float* ln1_b   = (const float*)d_in[7];
    const float* qkv_w   = (const float*)d_in[8];
    const float* qkv_b   = (const float*)d_in[9];
    const float* out_w   = (const float*)d_in[10];
    const float* out_b   = (const float*)d_in[11];
    const float* ln2_w   = (const float*)d_in[12];
    const float* ln2_b   = (const float*)d_in[13];
    const float* fc1_w   = (const float*)d_in[14];
    const float* fc1_b   = (const float*)d_in[15];
    const float* fc2_w   = (const float*)d_in[16];
    const float* fc2_b   = (const float*)d_in[17];
    const float* lnf_w   = (const float*)d_in[18];
    const float* lnf_b   = (const float*)d_in[19];
    float* outp = (float*)d_out;

    char* ws = (char*)d_ws;
    size_t off = 0;
    auto carve = [&](size_t bytes) {
        void* p = ws + off;
        off += al256(bytes);
        return p;
    };
    float*  hA      = (float*)carve((size_t)S_LEN * D_MODEL * 4);
    float*  hB      = (float*)carve((size_t)S_LEN * D_MODEL * 4);
    float*  qkvbuf  = (float*)carve((size_t)S_LEN * 3840 * 4);       // also g1 / W2r
    float*  aobuf   = (float*)carve((size_t)S_LEN * D_MODEL * 4);    // also W1r
    float*  f1buf   = (float*)carve((size_t)S_LEN * FF_DIM * 4);     // also A2
    int8_t* q8      = (int8_t*)carve((size_t)S_LEN * FF_DIM);        // also A1
    float*  sx      = (float*)carve((size_t)S_LEN * 4);
    int8_t* qw_qkv  = (int8_t*)carve((size_t)3840 * 1280);
    float*  ws_qkv  = (float*)carve((size_t)3840 * 4);
    int8_t* qw_out  = (int8_t*)carve((size_t)1280 * 1280);
    float*  ws_out  = (float*)carve((size_t)1280 * 4);
    int8_t* qw_fc1  = (int8_t*)carve((size_t)5120 * 1280);
    float*  ws_fc1  = (float*)carve((size_t)5120 * 4);
    int8_t* qw_fc2  = (int8_t*)carve((size_t)1280 * 5120);
    float*  ws_fc2  = (float*)carve((size_t)1280 * 4);
    (void)ws_size; (void)n_in; (void)in_sizes; (void)out_size;

    // conv stem aliases (all consumed before the transformer loop starts)
    // hi/lo bf16 planes occupy exactly the bytes the old f32 buffers used.
    unsigned short* A1h = (unsigned short*)q8;            // 3000*384*2*2 = 4.6 MB  <= 7.68 MB
    unsigned short* A1l = A1h + (size_t)3000 * 384;
    unsigned short* W1h = (unsigned short*)aobuf;         // 1280*384*2*2 = 2.0 MB  <= 7.68 MB
    unsigned short* W1l = W1h + (size_t)1280 * 384;
    float* g1 = qkvbuf;                                   // 3000*1280*4 = 15.4 MB <= 23 MB
    unsigned short* A2h = (unsigned short*)f1buf;         // 1500*3840*2*2 = 23 MB <= 30.7 MB
    unsigned short* A2l = A2h + (size_t)1500 * 3840;
    unsigned short* W2h = (unsigned short*)qkvbuf;        // 1280*3840*2*2 = 19.7 MB <= 23 MB (after g1 consumed)
    unsigned short* W2l = W2h + (size_t)1280 * 3840;

    // conv1: im2col (K=384) + bf16x3 MFMA GEMM + gelu -> g1[3000][1280]
    im2col1_kernel<<<dim3(12, 384), 256, 0, stream>>>(in_feat, A1h, A1l);
    wreorder_kernel<<<1280, 256, 0, stream>>>(conv1_w, W1h, W1l, 128);
    gemm_conv_bf16x3<0><<<240, 256, 0, stream>>>(A1h, A1l, W1h, W1l, conv1_b, nullptr, g1, 3000, 1280, 384, 10);
    // conv2: im2col (row concat, K=3840) + bf16x3 MFMA GEMM + gelu + pos -> hA[1500][1280]
    im2col2_kernel<<<dim3(15, 1500), 256, 0, stream>>>(g1, A2h, A2l);
    wreorder_kernel<<<1280, 256, 0, stream>>>(conv2_w, W2h, W2l, 1280);
    gemm_conv_bf16x3<1><<<120, 256, 0, stream>>>(A2h, A2l, W2h, W2l, conv2_b, pos_emb, hA, 1500, 1280, 3840, 10);

    float* h = hA;
    float* hn = hB;
    const int mtiles = (S_LEN + 63) / 64;  // 24

    for (int l = 0; l < N_LAYER; l++) {
        // quantize this layer's weights
        wquant_kernel<<<3840, 256, 0, stream>>>(qkv_w + (size_t)l * 3840 * 1280, qw_qkv, ws_qkv, 1280);
        wquant_kernel<<<1280, 256, 0, stream>>>(out_w + (size_t)l * 1280 * 1280, qw_out, ws_out, 1280);
        wquant_kernel<<<5120, 256, 0, stream>>>(fc1_w + (size_t)l * 5120 * 1280, qw_fc1, ws_fc1, 1280);
        wquant_kernel<<<1280, 256, 0, stream>>>(fc2_w + (size_t)l * 1280 * 5120, qw_fc2, ws_fc2, 5120);

        // attention block
        rmsnorm_quant_kernel<<<S_LEN, 256, 0, stream>>>(h, ln1_w + l * D_MODEL, ln1_b + l * D_MODEL, q8, sx);
        gemm_w8a8_mfma<<<dim3(60, mtiles), 256, 0, stream>>>(q8, sx, qw_qkv, ws_qkv,
            qkv_b + (size_t)l * 3840, nullptr, qkvbuf, S_LEN, 3840, 1280);
        attn_tiled_kernel<<<dim3(24, N_HEAD), 256, 0, stream>>>(qkvbuf, aobuf);
        quant_kernel<false><<<S_LEN, 256, 0, stream>>>(aobuf, q8, sx, D_MODEL);
        gemm_w8a8_mfma<<<dim3(20, mtiles), 256, 0, stream>>>(q8, sx, qw_out, ws_out,
            out_b + (size_t)l * 1280, h, hn, S_LEN, 1280, 1280);
        { float* t = h; h = hn; hn = t; }

        // MLP block
        rmsnorm_quant_kernel<<<S_LEN, 256, 0, stream>>>(h, ln2_w + l * D_MODEL, ln2_b + l * D_MODEL, q8, sx);
        gemm_w8a8_mfma<<<dim3(80, mtiles), 256, 0, stream>>>(q8, sx, qw_fc1, ws_fc1,
            fc1_b + (size_t)l * 5120, nullptr, f1buf, S_LEN, 5120, 1280);
        quant_kernel<true><<<S_LEN, 256, 0, stream>>>(f1buf, q8, sx, FF_DIM);
        gemm_w8a8_mfma<<<dim3(20, mtiles), 256, 0, stream>>>(q8, sx, qw_fc2, ws_fc2,
            fc2_b + (size_t)l * 1280, h, hn, S_LEN, 1280, 5120);
        { float* t = h; h = hn; hn = t; }
    }

    pool_ln_kernel<<<750, 256, 0, stream>>>(h, lnf_w, lnf_b, outp);
}

// Round 3
// 2282.845 us; speedup vs baseline: 1.2306x; 1.1527x over previous
//
#include <hip/hip_runtime.h>
#include <stdint.h>

#define S_LEN 1500
#define D_MODEL 1280
#define N_HEAD 20
#define D_HEAD 64
#define FF_DIM 5120
#define N_LAYER 4

typedef int v4i __attribute__((ext_vector_type(4)));
typedef short v8s __attribute__((ext_vector_type(8)));
typedef short v4s __attribute__((ext_vector_type(4)));
typedef float v4f __attribute__((ext_vector_type(4)));
typedef unsigned short ushort_t;

// ---------------- helpers ----------------

__device__ inline float gelu_tanh(float x) {
    // jax.nn.gelu default (approximate=True)
    float x3 = x * x * x;
    return 0.5f * x * (1.0f + tanhf(0.7978845608028654f * (x + 0.044715f * x3)));
}

__device__ inline float wred_sum(float v) {
    for (int o = 32; o > 0; o >>= 1) v += __shfl_down(v, o, 64);
    return v;
}
__device__ inline float wred_max(float v) {
    for (int o = 32; o > 0; o >>= 1) v = fmaxf(v, __shfl_down(v, o, 64));
    return v;
}
// blockDim.x == 256 (4 waves) assumed
__device__ inline float block_sum(float v, float* sm4) {
    v = wred_sum(v);
    int w = threadIdx.x >> 6;
    if ((threadIdx.x & 63) == 0) sm4[w] = v;
    __syncthreads();
    float r = sm4[0] + sm4[1] + sm4[2] + sm4[3];
    __syncthreads();
    return r;
}
__device__ inline float block_max(float v, float* sm4) {
    v = wred_max(v);
    int w = threadIdx.x >> 6;
    if ((threadIdx.x & 63) == 0) sm4[w] = v;
    __syncthreads();
    float r = fmaxf(fmaxf(sm4[0], sm4[1]), fmaxf(sm4[2], sm4[3]));
    __syncthreads();
    return r;
}

// f32 -> bf16 round-to-nearest-even, and back
__device__ inline unsigned short f2bf(float x) {
    unsigned int u = __float_as_uint(x);
    u += 0x7fffu + ((u >> 16) & 1u);
    return (unsigned short)(u >> 16);
}
__device__ inline float bf2f(unsigned short h) {
    return __uint_as_float(((unsigned int)h) << 16);
}

// async global->LDS, 16B per lane (wave-uniform LDS base + lane*16)
__device__ inline void gload_lds16(const void* g, void* l) {
    __builtin_amdgcn_global_load_lds(
        (const __attribute__((address_space(1))) char*)g,
        (__attribute__((address_space(3))) char*)l, 16, 0, 0);
}

// ---------------- conv stem: im2col + split-bf16 MFMA GEMM ----------------
// f32 operands are split x = hi + lo (both bf16, RNE). GEMM computes
// Ah*Bh + Al*Bh + Ah*Bl on the bf16 matrix cores with f32 accumulation;
// residual error ~2^-18 relative (f32-equivalent accuracy).

// A1[t][tap*128+i] = in[i][t-1+tap], t in [0,3000)  (hi/lo bf16 planes)
__global__ __launch_bounds__(256) void im2col1_kernel(
    const float* __restrict__ x, unsigned short* __restrict__ Ah,
    unsigned short* __restrict__ Al)
{
    int t = blockIdx.x * 256 + threadIdx.x;
    int col = blockIdx.y;  // 0..383
    if (t >= 3000) return;
    int tap = col >> 7, i = col & 127;
    int src = t - 1 + tap;
    float v = (src >= 0 && src < 3000) ? x[(size_t)i * 3000 + src] : 0.0f;
    unsigned short h = f2bf(v);
    Ah[(size_t)t * 384 + col] = h;
    Al[(size_t)t * 384 + col] = f2bf(v - bf2f(h));
}

// A2[t][tap*1280+o] = g1[2t-1+tap][o], t in [0,1500)  (hi/lo bf16 planes)
__global__ __launch_bounds__(256) void im2col2_kernel(
    const float* __restrict__ g1, unsigned short* __restrict__ Ah,
    unsigned short* __restrict__ Al)
{
    int col = blockIdx.x * 256 + threadIdx.x;  // 0..3839
    int t = blockIdx.y;
    if (col >= 3840) return;
    int tap = col / 1280, o = col - tap * 1280;
    int src = 2 * t - 1 + tap;
    float v = (src >= 0 && src < 3000) ? g1[(size_t)src * 1280 + o] : 0.0f;
    unsigned short h = f2bf(v);
    Ah[(size_t)t * 3840 + col] = h;
    Al[(size_t)t * 3840 + col] = f2bf(v - bf2f(h));
}

// out[o][tap*C+i] = w[o][i][tap]  (hi/lo bf16 planes)
__global__ __launch_bounds__(256) void wreorder_kernel(
    const float* __restrict__ w, unsigned short* __restrict__ woh,
    unsigned short* __restrict__ wol, int C)
{
    int o = blockIdx.x;
    int KC = 3 * C;
    const float* wr = w + (size_t)o * KC;
    for (int col = threadIdx.x; col < KC; col += 256) {
        int tap = col / C, i = col - tap * C;
        float v = wr[i * 3 + tap];
        unsigned short h = f2bf(v);
        woh[(size_t)o * KC + col] = h;
        wol[(size_t)o * KC + col] = f2bf(v - bf2f(h));
    }
}

// C[m][n] = gelu(A[m,:].W[n,:] + bias[n]) (+ pos[m][n] if EPI==1)
// 128x128 tile, 4 waves (2x2, each 64x64), LDS double-buffered via
// global_load_lds width=16 (m97 structure), XCD-swizzled flat grid.
// Planes staged per buffer: 0=Ah 1=Al 2=Bh 3=Bl, each [128][32] bf16.
template <int EPI>
__global__ __launch_bounds__(256, 2) void gemm_conv_bf16x3(
    const unsigned short* __restrict__ Ah, const unsigned short* __restrict__ Al,
    const unsigned short* __restrict__ Wh, const unsigned short* __restrict__ Wl,
    const float* __restrict__ bias, const float* __restrict__ pos,
    float* __restrict__ out, int M, int N, int K, int nTilesN)
{
    __shared__ unsigned short lds[2][4][128][32];   // 64 KB
    int tid = threadIdx.x;
    int lane = tid & 63;
    int wv = tid >> 6;
    int l15 = lane & 15, quad = lane >> 4;
    int wm = wv >> 1, wn = wv & 1;   // 2x2 wave grid

    // bijective XCD swizzle (gridDim.x % 8 == 0)
    int nwg = gridDim.x;
    int cpx = nwg >> 3;
    int bid = blockIdx.x;
    int swz = (bid & 7) * cpx + (bid >> 3);
    int bx = swz % nTilesN, by = swz / nTilesN;
    int m0 = by * 128, n0 = bx * 128;

    // wave wv stages plane wv: 8 chunks x 1024B; lane -> row (lane>>2), 16B slot (lane&3)
    const unsigned short* splane = (wv == 0) ? Ah : (wv == 1) ? Al : (wv == 2) ? Wh : Wl;
    int rbase = (wv < 2) ? m0 : n0;
    int rlim  = (wv < 2) ? M : N;
    const unsigned short* srcp[8];
    #pragma unroll
    for (int c = 0; c < 8; c++) {
        int row = rbase + c * 16 + (lane >> 2);
        if (row >= rlim) row = rlim - 1;
        srcp[c] = splane + (size_t)row * K + (lane & 3) * 8;
    }

    auto stage = [&](int nb, int k0) {
        char* lbase = (char*)&lds[nb][wv][0][0];
        #pragma unroll
        for (int c = 0; c < 8; c++)
            gload_lds16(srcp[c] + k0, lbase + c * 1024);
    };

    v4f acc[4][4];
    #pragma unroll
    for (int i = 0; i < 4; i++)
        #pragma unroll
        for (int j = 0; j < 4; j++) acc[i][j] = (v4f){0.0f, 0.0f, 0.0f, 0.0f};

    int nsteps = K >> 5;
    stage(0, 0);
    __syncthreads();   // buf0 staged (vmcnt drain at barrier)
    int cur = 0;
    for (int t = 0; t < nsteps; t++) {
        if (t + 1 < nsteps) stage(cur ^ 1, (t + 1) * 32);   // prefetch next (hidden under MFMA)
        v8s ah[4], al2[4], bh[4], bl[4];
        #pragma unroll
        for (int i = 0; i < 4; i++) {
            ah[i]  = *(const v8s*)&lds[cur][0][wm * 64 + i * 16 + l15][quad * 8];
            al2[i] = *(const v8s*)&lds[cur][1][wm * 64 + i * 16 + l15][quad * 8];
            bh[i]  = *(const v8s*)&lds[cur][2][wn * 64 + i * 16 + l15][quad * 8];
            bl[i]  = *(const v8s*)&lds[cur][3][wn * 64 + i * 16 + l15][quad * 8];
        }
        #pragma unroll
        for (int i = 0; i < 4; i++)
            #pragma unroll
            for (int j = 0; j < 4; j++) {
                acc[i][j] = __builtin_amdgcn_mfma_f32_16x16x32_bf16(ah[i],  bh[j], acc[i][j], 0, 0, 0);
                acc[i][j] = __builtin_amdgcn_mfma_f32_16x16x32_bf16(al2[i], bh[j], acc[i][j], 0, 0, 0);
                acc[i][j] = __builtin_amdgcn_mfma_f32_16x16x32_bf16(ah[i],  bl[j], acc[i][j], 0, 0, 0);
            }
        __syncthreads();   // drains prefetch + all reads of lds[cur] done
        cur ^= 1;
    }

    #pragma unroll
    for (int i = 0; i < 4; i++) {
        #pragma unroll
        for (int j = 0; j < 4; j++) {
            int n = n0 + wn * 64 + j * 16 + l15;
            float bn = bias[n];
            #pragma unroll
            for (int r = 0; r < 4; r++) {
                int m = m0 + wm * 64 + i * 16 + quad * 4 + r;
                if (m < M) {
                    float v = gelu_tanh(acc[i][j][r] + bn);
                    if (EPI == 1) v += pos[(size_t)m * N + n];
                    out[(size_t)m * N + n] = v;
                }
            }
        }
    }
}

// ---------------- quantization kernels ----------------

// per-row weight quant: block per row, float4
__global__ __launch_bounds__(256) void wquant_kernel(
    const float* __restrict__ w, int8_t* __restrict__ qw,
    float* __restrict__ ws, int K)
{
    int r = blockIdx.x;
    int tid = threadIdx.x;
    __shared__ float sm4[4];
    const float4* wr = (const float4*)(w + (size_t)r * K);
    int n4 = K >> 2;
    float mx = 0.0f;
    for (int i = tid; i < n4; i += 256) {
        float4 v = wr[i];
        mx = fmaxf(mx, fmaxf(fmaxf(fabsf(v.x), fabsf(v.y)), fmaxf(fabsf(v.z), fabsf(v.w))));
    }
    mx = block_max(mx, sm4);
    float sc = fmaxf(mx / 127.0f, 1e-8f);
    if (tid == 0) ws[r] = sc;
    float rs = 1.0f / sc;
    char4* qr = (char4*)(qw + (size_t)r * K);
    for (int i = tid; i < n4; i += 256) {
        float4 v = wr[i];
        char4 q;
        q.x = (int8_t)fminf(fmaxf(rintf(v.x * rs), -128.0f), 127.0f);
        q.y = (int8_t)fminf(fmaxf(rintf(v.y * rs), -128.0f), 127.0f);
        q.z = (int8_t)fminf(fmaxf(rintf(v.z * rs), -128.0f), 127.0f);
        q.w = (int8_t)fminf(fmaxf(rintf(v.w * rs), -128.0f), 127.0f);
        qr[i] = q;
    }
}

// RMSNorm + per-token quant, D=1280, block per token
__global__ __launch_bounds__(256) void rmsnorm_quant_kernel(
    const float* __restrict__ x, const float* __restrict__ w,
    const float* __restrict__ b, int8_t* __restrict__ q,
    float* __restrict__ sx)
{
    int s = blockIdx.x;
    int tid = threadIdx.x;
    __shared__ float sm4[4];
    const float* xr = x + (size_t)s * D_MODEL;
    float v[5];
    float ss = 0.0f;
    for (int i = 0; i < 5; i++) {
        float t = xr[tid + 256 * i];
        v[i] = t;
        ss += t * t;
    }
    ss = block_sum(ss, sm4);
    float inv = rsqrtf(ss * (1.0f / 1280.0f) + 1e-6f);
    float mx = 0.0f;
    for (int i = 0; i < 5; i++) {
        int idx = tid + 256 * i;
        float t = v[i] * inv * w[idx] + b[idx];
        v[i] = t;
        mx = fmaxf(mx, fabsf(t));
    }
    mx = block_max(mx, sm4);
    float sc = fmaxf(mx / 127.0f, 1e-8f);
    if (tid == 0) sx[s] = sc;
    float rs = 1.0f / sc;
    for (int i = 0; i < 5; i++) {
        float qv = rintf(v[i] * rs);
        qv = fminf(fmaxf(qv, -128.0f), 127.0f);
        q[(size_t)s * D_MODEL + tid + 256 * i] = (int8_t)qv;
    }
}

// per-token quant (optionally fused gelu); block per token
template <bool GELU>
__global__ __launch_bounds__(256) void quant_kernel(
    const float* __restrict__ x, int8_t* __restrict__ q,
    float* __restrict__ sx, int Dm)
{
    int s = blockIdx.x;
    int tid = threadIdx.x;
    __shared__ float sm4[4];
    const float4* xr = (const float4*)(x + (size_t)s * Dm);
    int n4 = Dm >> 2;
    float mx = 0.0f;
    for (int i = tid; i < n4; i += 256) {
        float4 t = xr[i];
        if (GELU) { t.x = gelu_tanh(t.x); t.y = gelu_tanh(t.y); t.z = gelu_tanh(t.z); t.w = gelu_tanh(t.w); }
        mx = fmaxf(mx, fmaxf(fmaxf(fabsf(t.x), fabsf(t.y)), fmaxf(fabsf(t.z), fabsf(t.w))));
    }
    mx = block_max(mx, sm4);
    float sc = fmaxf(mx / 127.0f, 1e-8f);
    if (tid == 0) sx[s] = sc;
    float rs = 1.0f / sc;
    char4* qr = (char4*)(q + (size_t)s * Dm);
    for (int i = tid; i < n4; i += 256) {
        float4 t = xr[i];
        if (GELU) { t.x = gelu_tanh(t.x); t.y = gelu_tanh(t.y); t.z = gelu_tanh(t.z); t.w = gelu_tanh(t.w); }
        char4 qq;
        qq.x = (int8_t)fminf(fmaxf(rintf(t.x * rs), -128.0f), 127.0f);
        qq.y = (int8_t)fminf(fmaxf(rintf(t.y * rs), -128.0f), 127.0f);
        qq.z = (int8_t)fminf(fmaxf(rintf(t.z * rs), -128.0f), 127.0f);
        qq.w = (int8_t)fminf(fmaxf(rintf(t.w * rs), -128.0f), 127.0f);
        qr[i] = qq;
    }
}

// ---------------- int8 GEMM via MFMA ----------------
// out[m,n] = (sum_k qx[m,k]*qw[n,k]) * sx[m] * ws[n] + bias[n] (+ res[m,n])
__global__ __launch_bounds__(256) void gemm_w8a8_mfma(
    const int8_t* __restrict__ qx, const float* __restrict__ sx,
    const int8_t* __restrict__ qw, const float* __restrict__ ws,
    const float* __restrict__ bias, const float* __restrict__ res,
    float* __restrict__ out, int M, int O, int K)
{
    int lane = threadIdx.x & 63;
    int wv = threadIdx.x >> 6;
    int l15 = lane & 15;
    int quad = lane >> 4;
    int m_base = blockIdx.y * 64 + wv * 16;
    int n_base = blockIdx.x * 64;

    int ar = m_base + l15; if (ar >= M) ar = M - 1;
    const int8_t* ap = qx + (size_t)ar * K + quad * 16;
    const int8_t* bp = qw + (size_t)(n_base + l15) * K + quad * 16;
    size_t rowK16 = (size_t)16 * K;

    v4i acc0 = {0, 0, 0, 0}, acc1 = {0, 0, 0, 0}, acc2 = {0, 0, 0, 0}, acc3 = {0, 0, 0, 0};
    int nsteps = K >> 6;
    for (int s = 0; s < nsteps; s++) {
        v4i a  = *(const v4i*)(ap + s * 64);
        v4i b0 = *(const v4i*)(bp + s * 64);
        v4i b1 = *(const v4i*)(bp + rowK16 + s * 64);
        v4i b2 = *(const v4i*)(bp + 2 * rowK16 + s * 64);
        v4i b3 = *(const v4i*)(bp + 3 * rowK16 + s * 64);
        acc0 = __builtin_amdgcn_mfma_i32_16x16x64_i8(a, b0, acc0, 0, 0, 0);
        acc1 = __builtin_amdgcn_mfma_i32_16x16x64_i8(a, b1, acc1, 0, 0, 0);
        acc2 = __builtin_amdgcn_mfma_i32_16x16x64_i8(a, b2, acc2, 0, 0, 0);
        acc3 = __builtin_amdgcn_mfma_i32_16x16x64_i8(a, b3, acc3, 0, 0, 0);
    }

    float sxv[4];
    #pragma unroll
    for (int r = 0; r < 4; r++) {
        int m = m_base + quad * 4 + r;
        sxv[r] = (m < M) ? sx[m] : 0.0f;
    }
    v4i accs[4] = {acc0, acc1, acc2, acc3};
    #pragma unroll
    for (int nb = 0; nb < 4; nb++) {
        int n = n_base + nb * 16 + l15;
        float wn = ws[n];
        float bn = bias[n];
        #pragma unroll
        for (int r = 0; r < 4; r++) {
            int m = m_base + quad * 4 + r;
            if (m < M) {
                float y = (float)accs[nb][r] * sxv[r] * wn + bn;
                if (res) y += res[(size_t)m * O + n];
                out[(size_t)m * O + n] = y;
            }
        }
    }
}

// ---------------- attention: flash-style with split-bf16 MFMA ----------------
// grid (24 q-tiles, 20 heads), 256 threads (4 waves, 16 q-rows each).
// QK^T and PV on matrix cores with hi/lo bf16 split (f32-equivalent).
// qkv layout [S][3840] with q|k|v each [H][64].
// LDS rows padded to 72 elements (144 B): 16B-aligned v8s frags, no pow2 stride.
__global__ __launch_bounds__(256, 2) void attn_mfma_kernel(
    const float* __restrict__ qkv, float* __restrict__ ao)
{
    __shared__ ushort_t Kh[64][72], Kl[64][72];   // K tile [k][d]
    __shared__ ushort_t Vh[64][72], Vl[64][72];   // V tile transposed [d][k]
    __shared__ ushort_t Ph[64][72], Pl[64][72];   // P tile [q][k]
    int h = blockIdx.y;
    int q_tile = blockIdx.x;
    int tid = threadIdx.x;
    int lane = tid & 63;
    int wv = tid >> 6;
    int l15 = lane & 15, quad = lane >> 4;

    // ---- Q fragments to registers (hi/lo), A-operand layout ----
    // lane l15 = q-row (within wave's 16), quad*8+j = d (per 32-wide k-step)
    int qg = q_tile * 64 + wv * 16 + l15;
    int qc = qg < S_LEN ? qg : S_LEN - 1;
    const float* qsrc = qkv + (size_t)qc * 3840 + h * 64;
    v8s qh[2], ql[2];
    #pragma unroll
    for (int ks = 0; ks < 2; ks++) {
        const float4* p4 = (const float4*)(qsrc + ks * 32 + quad * 8);
        float4 a = p4[0], b = p4[1];
        float f[8] = {a.x, a.y, a.z, a.w, b.x, b.y, b.z, b.w};
        #pragma unroll
        for (int j = 0; j < 8; j++) {
            unsigned short hh = f2bf(f[j]);
            qh[ks][j] = (short)hh;
            ql[ks][j] = (short)f2bf(f[j] - bf2f(hh));
        }
    }

    v4f O[4];
    #pragma unroll
    for (int nb = 0; nb < 4; nb++) O[nb] = (v4f){0.0f, 0.0f, 0.0f, 0.0f};
    float m_run[4], l_run[4];
    #pragma unroll
    for (int r = 0; r < 4; r++) { m_run[r] = -INFINITY; l_run[r] = 0.0f; }

    // staging thread mappings
    int sk = tid >> 2, sd = (tid & 3) * 16;          // K: row sk, 16 d's
    int vk = (tid & 15) * 4, vd = (tid >> 4) * 4;    // V: 4x4 block transpose

    for (int kt = 0; kt < 24; kt++) {
        int kbase = kt * 64;
        int krem = S_LEN - kbase;   // valid keys in this tile (>=28)

        __syncthreads();   // prev iter PV reads of V/P done (covers Q-load iter0)

        // ---- stage K tile [k][d] bf16 hi/lo ----
        {
            int kg2 = kbase + sk;
            int kc2 = kg2 < S_LEN ? kg2 : S_LEN - 1;
            const float* src = qkv + (size_t)kc2 * 3840 + 1280 + h * 64 + sd;
            float f[16];
            *(float4*)&f[0]  = ((const float4*)src)[0];
            *(float4*)&f[4]  = ((const float4*)src)[1];
            *(float4*)&f[8]  = ((const float4*)src)[2];
            *(float4*)&f[12] = ((const float4*)src)[3];
            v8s h0, h1, l0, l1;
            #pragma unroll
            for (int j = 0; j < 8; j++) {
                unsigned short u0 = f2bf(f[j]);
                unsigned short u1 = f2bf(f[8 + j]);
                h0[j] = (short)u0; l0[j] = (short)f2bf(f[j] - bf2f(u0));
                h1[j] = (short)u1; l1[j] = (short)f2bf(f[8 + j] - bf2f(u1));
            }
            *(v8s*)&Kh[sk][sd] = h0; *(v8s*)&Kh[sk][sd + 8] = h1;
            *(v8s*)&Kl[sk][sd] = l0; *(v8s*)&Kl[sk][sd + 8] = l1;
        }
        // ---- stage V tile transposed [d][k] bf16 hi/lo ----
        {
            float vals[4][4];
            #pragma unroll
            for (int i = 0; i < 4; i++) {
                int kg2 = kbase + vk + i;
                int kc2 = kg2 < S_LEN ? kg2 : S_LEN - 1;
                *(float4*)&vals[i][0] =
                    *(const float4*)(qkv + (size_t)kc2 * 3840 + 2560 + h * 64 + vd);
            }
            #pragma unroll
            for (int j = 0; j < 4; j++) {
                v4s hv, lv;
                #pragma unroll
                for (int i = 0; i < 4; i++) {
                    unsigned short u = f2bf(vals[i][j]);
                    hv[i] = (short)u;
                    lv[i] = (short)f2bf(vals[i][j] - bf2f(u));
                }
                *(v4s*)&Vh[vd + j][vk] = hv;
                *(v4s*)&Vl[vd + j][vk] = lv;
            }
        }
        __syncthreads();

        // ---- QK^T via MFMA: S[64q][64k], split hi/lo x3 ----
        v4f S[4];
        #pragma unroll
        for (int nb = 0; nb < 4; nb++) S[nb] = (v4f){0.0f, 0.0f, 0.0f, 0.0f};
        #pragma unroll
        for (int ks = 0; ks < 2; ks++) {
            #pragma unroll
            for (int nb = 0; nb < 4; nb++) {
                v8s kbh = *(const v8s*)&Kh[nb * 16 + l15][ks * 32 + quad * 8];
                v8s kbl = *(const v8s*)&Kl[nb * 16 + l15][ks * 32 + quad * 8];
                S[nb] = __builtin_amdgcn_mfma_f32_16x16x32_bf16(qh[ks], kbh, S[nb], 0, 0, 0);
                S[nb] = __builtin_amdgcn_mfma_f32_16x16x32_bf16(ql[ks], kbh, S[nb], 0, 0, 0);
                S[nb] = __builtin_amdgcn_mfma_f32_16x16x32_bf16(qh[ks], kbl, S[nb], 0, 0, 0);
            }
        }

        // scale + mask (C layout: row q = quad*4+r, col k = nb*16+l15)
        #pragma unroll
        for (int nb = 0; nb < 4; nb++) {
            bool valid = (nb * 16 + l15) < krem;
            #pragma unroll
            for (int r = 0; r < 4; r++) {
                float s = S[nb][r] * 0.125f;
                S[nb][r] = valid ? s : -INFINITY;
            }
        }

        // online softmax: reduce over cols = local (nb) + shfl over l15 group
        #pragma unroll
        for (int r = 0; r < 4; r++) {
            float t = fmaxf(fmaxf(S[0][r], S[1][r]), fmaxf(S[2][r], S[3][r]));
            #pragma unroll
            for (int msk = 1; msk < 16; msk <<= 1)
                t = fmaxf(t, __shfl_xor(t, msk, 64));
            float mn = fmaxf(m_run[r], t);
            float alpha = __expf(m_run[r] - mn);
            m_run[r] = mn;
            float rs = 0.0f;
            #pragma unroll
            for (int nb = 0; nb < 4; nb++) {
                float p = __expf(S[nb][r] - mn);
                S[nb][r] = p;
                rs += p;
            }
            #pragma unroll
            for (int msk = 1; msk < 16; msk <<= 1)
                rs += __shfl_xor(rs, msk, 64);
            l_run[r] = l_run[r] * alpha + rs;
            #pragma unroll
            for (int nb = 0; nb < 4; nb++) O[nb][r] *= alpha;
        }

        // store P hi/lo to LDS (rows wv*16 + quad*4 + r)
        #pragma unroll
        for (int nb = 0; nb < 4; nb++) {
            #pragma unroll
            for (int r = 0; r < 4; r++) {
                float p = S[nb][r];
                unsigned short hp = f2bf(p);
                Ph[wv * 16 + quad * 4 + r][nb * 16 + l15] = hp;
                Pl[wv * 16 + quad * 4 + r][nb * 16 + l15] = f2bf(p - bf2f(hp));
            }
        }
        __syncthreads();   // P visible; K reads done (V/P reads next)

        // ---- PV via MFMA: O[64q][64d] += P x V, split x3 ----
        #pragma unroll
        for (int ks = 0; ks < 2; ks++) {
            v8s pah = *(const v8s*)&Ph[wv * 16 + l15][ks * 32 + quad * 8];
            v8s pal = *(const v8s*)&Pl[wv * 16 + l15][ks * 32 + quad * 8];
            #pragma unroll
            for (int nb = 0; nb < 4; nb++) {
                v8s vbh = *(const v8s*)&Vh[nb * 16 + l15][ks * 32 + quad * 8];
                v8s vbl = *(const v8s*)&Vl[nb * 16 + l15][ks * 32 + quad * 8];
                O[nb] = __builtin_amdgcn_mfma_f32_16x16x32_bf16(pah, vbh, O[nb], 0, 0, 0);
                O[nb] = __builtin_amdgcn_mfma_f32_16x16x32_bf16(pal, vbh, O[nb], 0, 0, 0);
                O[nb] = __builtin_amdgcn_mfma_f32_16x16x32_bf16(pah, vbl, O[nb], 0, 0, 0);
            }
        }
    }

    // epilogue (C layout: row q = wv*16 + quad*4 + r, col d = nb*16 + l15)
    #pragma unroll
    for (int r = 0; r < 4; r++) {
        int qg2 = q_tile * 64 + wv * 16 + quad * 4 + r;
        if (qg2 < S_LEN) {
            float rl = 1.0f / l_run[r];
            #pragma unroll
            for (int nb = 0; nb < 4; nb++)
                ao[(size_t)qg2 * D_MODEL + h * 64 + nb * 16 + l15] = O[nb][r] * rl;
        }
    }
}

// ---------------- final pool + layernorm ----------------
__global__ __launch_bounds__(256) void pool_ln_kernel(
    const float* __restrict__ h, const float* __restrict__ w,
    const float* __restrict__ b, float* __restrict__ out)
{
    int t = blockIdx.x;
    int tid = threadIdx.x;
    __shared__ float sm4[4];
    const float* r0 = h + (size_t)(2 * t) * D_MODEL;
    const float* r1 = r0 + D_MODEL;
    float v[5];
    float s1 = 0.0f;
    for (int i = 0; i < 5; i++) {
        int idx = tid + 256 * i;
        float x = 0.5f * (r0[idx] + r1[idx]);
        v[i] = x;
        s1 += x;
    }
    float mu = block_sum(s1, sm4) * (1.0f / 1280.0f);
    float s2 = 0.0f;
    for (int i = 0; i < 5; i++) {
        float d = v[i] - mu;
        s2 += d * d;
    }
    float var = block_sum(s2, sm4) * (1.0f / 1280.0f);
    float inv = rsqrtf(var + 1e-5f);
    for (int i = 0; i < 5; i++) {
        int idx = tid + 256 * i;
        out[(size_t)t * D_MODEL + idx] = (v[i] - mu) * inv * w[idx] + b[idx];
    }
}

// ---------------- host ----------------

static inline size_t al256(size_t x) { return (x + 255) & ~(size_t)255; }

extern "C" void kernel_launch(void* const* d_in, const int* in_sizes, int n_in,
                              void* d_out, int out_size, void* d_ws, size_t ws_size,
                              hipStream_t stream) {
    const float* in_feat = (const float*)d_in[0];   // [1][128][3000]
    const float* conv1_w = (const float*)d_in[1];
    const float* conv1_b = (const float*)d_in[2];
    const float* conv2_w = (const float*)d_in[3];
    const float* conv2_b = (const float*)d_in[4];
    const float* pos_emb = (const float*)d_in[5];
    const float* ln1_w   = (const float*)d_in[6];
    const float* ln1_b   = (const float*)d_in[7];
    const float* qkv_w   = (const float*)d_in[8];
    const float* qkv_b   = (const float*)d_in[9];
    const float* out_w   = (const float*)d_in[10];
    const float* out_b   = (const float*)d_in[11];
    const float* ln2_w   = (const float*)d_in[12];
    const float* ln2_b   = (const float*)d_in[13];
    const float* fc1_w   = (const float*)d_in[14];
    const float* fc1_b   = (const float*)d_in[15];
    const float* fc2_w   = (const float*)d_in[16];
    const float* fc2_b   = (const float*)d_in[17];
    const float* lnf_w   = (const float*)d_in[18];
    const float* lnf_b   = (const float*)d_in[19];
    float* outp = (float*)d_out;

    char* ws = (char*)d_ws;
    size_t off = 0;
    auto carve = [&](size_t bytes) {
        void* p = ws + off;
        off += al256(bytes);
        return p;
    };
    float*  hA      = (float*)carve((size_t)S_LEN * D_MODEL * 4);
    float*  hB      = (float*)carve((size_t)S_LEN * D_MODEL * 4);
    float*  qkvbuf  = (float*)carve((size_t)S_LEN * 3840 * 4);       // also g1 / W2r
    float*  aobuf   = (float*)carve((size_t)S_LEN * D_MODEL * 4);    // also W1r
    float*  f1buf   = (float*)carve((size_t)S_LEN * FF_DIM * 4);     // also A2
    int8_t* q8      = (int8_t*)carve((size_t)S_LEN * FF_DIM);        // also A1
    float*  sx      = (float*)carve((size_t)S_LEN * 4);
    int8_t* qw_qkv  = (int8_t*)carve((size_t)3840 * 1280);
    float*  ws_qkv  = (float*)carve((size_t)3840 * 4);
    int8_t* qw_out  = (int8_t*)carve((size_t)1280 * 1280);
    float*  ws_out  = (float*)carve((size_t)1280 * 4);
    int8_t* qw_fc1  = (int8_t*)carve((size_t)5120 * 1280);
    float*  ws_fc1  = (float*)carve((size_t)5120 * 4);
    int8_t* qw_fc2  = (int8_t*)carve((size_t)1280 * 5120);
    float*  ws_fc2  = (float*)carve((size_t)1280 * 4);
    (void)ws_size; (void)n_in; (void)in_sizes; (void)out_size;

    // conv stem aliases (all consumed before the transformer loop starts)
    // hi/lo bf16 planes occupy exactly the bytes the old f32 buffers used.
    unsigned short* A1h = (unsigned short*)q8;            // 3000*384*2*2 = 4.6 MB  <= 7.68 MB
    unsigned short* A1l = A1h + (size_t)3000 * 384;
    unsigned short* W1h = (unsigned short*)aobuf;         // 1280*384*2*2 = 2.0 MB  <= 7.68 MB
    unsigned short* W1l = W1h + (size_t)1280 * 384;
    float* g1 = qkvbuf;                                   // 3000*1280*4 = 15.4 MB <= 23 MB
    unsigned short* A2h = (unsigned short*)f1buf;         // 1500*3840*2*2 = 23 MB <= 30.7 MB
    unsigned short* A2l = A2h + (size_t)1500 * 3840;
    unsigned short* W2h = (unsigned short*)qkvbuf;        // 1280*3840*2*2 = 19.7 MB <= 23 MB (after g1 consumed)
    unsigned short* W2l = W2h + (size_t)1280 * 3840;

    // conv1: im2col (K=384) + bf16x3 MFMA GEMM + gelu -> g1[3000][1280]
    im2col1_kernel<<<dim3(12, 384), 256, 0, stream>>>(in_feat, A1h, A1l);
    wreorder_kernel<<<1280, 256, 0, stream>>>(conv1_w, W1h, W1l, 128);
    gemm_conv_bf16x3<0><<<240, 256, 0, stream>>>(A1h, A1l, W1h, W1l, conv1_b, nullptr, g1, 3000, 1280, 384, 10);
    // conv2: im2col (row concat, K=3840) + bf16x3 MFMA GEMM + gelu + pos -> hA[1500][1280]
    im2col2_kernel<<<dim3(15, 1500), 256, 0, stream>>>(g1, A2h, A2l);
    wreorder_kernel<<<1280, 256, 0, stream>>>(conv2_w, W2h, W2l, 1280);
    gemm_conv_bf16x3<1><<<120, 256, 0, stream>>>(A2h, A2l, W2h, W2l, conv2_b, pos_emb, hA, 1500, 1280, 3840, 10);

    float* h = hA;
    float* hn = hB;
    const int mtiles = (S_LEN + 63) / 64;  // 24

    for (int l = 0; l < N_LAYER; l++) {
        // quantize this layer's weights
        wquant_kernel<<<3840, 256, 0, stream>>>(qkv_w + (size_t)l * 3840 * 1280, qw_qkv, ws_qkv, 1280);
        wquant_kernel<<<1280, 256, 0, stream>>>(out_w + (size_t)l * 1280 * 1280, qw_out, ws_out, 1280);
        wquant_kernel<<<5120, 256, 0, stream>>>(fc1_w + (size_t)l * 5120 * 1280, qw_fc1, ws_fc1, 1280);
        wquant_kernel<<<1280, 256, 0, stream>>>(fc2_w + (size_t)l * 1280 * 5120, qw_fc2, ws_fc2, 5120);

        // attention block
        rmsnorm_quant_kernel<<<S_LEN, 256, 0, stream>>>(h, ln1_w + l * D_MODEL, ln1_b + l * D_MODEL, q8, sx);
        gemm_w8a8_mfma<<<dim3(60, mtiles), 256, 0, stream>>>(q8, sx, qw_qkv, ws_qkv,
            qkv_b + (size_t)l * 3840, nullptr, qkvbuf, S_LEN, 3840, 1280);
        attn_mfma_kernel<<<dim3(24, N_HEAD), 256, 0, stream>>>(qkvbuf, aobuf);
        quant_kernel<false><<<S_LEN, 256, 0, stream>>>(aobuf, q8, sx, D_MODEL);
        gemm_w8a8_mfma<<<dim3(20, mtiles), 256, 0, stream>>>(q8, sx, qw_out, ws_out,
            out_b + (size_t)l * 1280, h, hn, S_LEN, 1280, 1280);
        { float* t = h; h = hn; hn = t; }

        // MLP block
        rmsnorm_quant_kernel<<<S_LEN, 256, 0, stream>>>(h, ln2_w + l * D_MODEL, ln2_b + l * D_MODEL, q8, sx);
        gemm_w8a8_mfma<<<dim3(80, mtiles), 256, 0, stream>>>(q8, sx, qw_fc1, ws_fc1,
            fc1_b + (size_t)l * 5120, nullptr, f1buf, S_LEN, 5120, 1280);
        quant_kernel<true><<<S_LEN, 256, 0, stream>>>(f1buf, q8, sx, FF_DIM);
        gemm_w8a8_mfma<<<dim3(20, mtiles), 256, 0, stream>>>(q8, sx, qw_fc2, ws_fc2,
            fc2_b + (size_t)l * 1280, h, hn, S_LEN, 1280, 5120);
        { float* t = h; h = hn; hn = t; }
    }

    pool_ln_kernel<<<750, 256, 0, stream>>>(h, lnf_w, lnf_b, outp);
}

// Round 4
// 2200.484 us; speedup vs baseline: 1.2767x; 1.0374x over previous
//
#include <hip/hip_runtime.h>
#include <stdint.h>

#define S_LEN 1500
#define D_MODEL 1280
#define N_HEAD 20
#define D_HEAD 64
#define FF_DIM 5120
#define N_LAYER 4

typedef int v4i __attribute__((ext_vector_type(4)));
typedef short v8s __attribute__((ext_vector_type(8)));
typedef short v4s __attribute__((ext_vector_type(4)));
typedef float v4f __attribute__((ext_vector_type(4)));
typedef unsigned short ushort_t;

// ---------------- helpers ----------------

__device__ inline float gelu_tanh(float x) {
    // jax.nn.gelu default (approximate=True)
    float x3 = x * x * x;
    return 0.5f * x * (1.0f + tanhf(0.7978845608028654f * (x + 0.044715f * x3)));
}

__device__ inline float wred_sum(float v) {
    for (int o = 32; o > 0; o >>= 1) v += __shfl_down(v, o, 64);
    return v;
}
__device__ inline float wred_max(float v) {
    for (int o = 32; o > 0; o >>= 1) v = fmaxf(v, __shfl_down(v, o, 64));
    return v;
}
// blockDim.x == 256 (4 waves) assumed
__device__ inline float block_sum(float v, float* sm4) {
    v = wred_sum(v);
    int w = threadIdx.x >> 6;
    if ((threadIdx.x & 63) == 0) sm4[w] = v;
    __syncthreads();
    float r = sm4[0] + sm4[1] + sm4[2] + sm4[3];
    __syncthreads();
    return r;
}
__device__ inline float block_max(float v, float* sm4) {
    v = wred_max(v);
    int w = threadIdx.x >> 6;
    if ((threadIdx.x & 63) == 0) sm4[w] = v;
    __syncthreads();
    float r = fmaxf(fmaxf(sm4[0], sm4[1]), fmaxf(sm4[2], sm4[3]));
    __syncthreads();
    return r;
}

// f32 -> bf16 round-to-nearest-even, and back
__device__ inline unsigned short f2bf(float x) {
    unsigned int u = __float_as_uint(x);
    u += 0x7fffu + ((u >> 16) & 1u);
    return (unsigned short)(u >> 16);
}
__device__ inline float bf2f(unsigned short h) {
    return __uint_as_float(((unsigned int)h) << 16);
}

// async global->LDS, 16B per lane (wave-uniform LDS base + lane*16)
__device__ inline void gload_lds16(const void* g, void* l) {
    __builtin_amdgcn_global_load_lds(
        (const __attribute__((address_space(1))) char*)g,
        (__attribute__((address_space(3))) char*)l, 16, 0, 0);
}

// ---------------- conv stem: im2col + split-bf16 MFMA GEMM ----------------
// f32 operands are split x = hi + lo (both bf16, RNE). GEMM computes
// Ah*Bh + Al*Bh + Ah*Bl on the bf16 matrix cores with f32 accumulation;
// residual error ~2^-18 relative (f32-equivalent accuracy).

// A1[t][tap*128+i] = in[i][t-1+tap], t in [0,3000)  (hi/lo bf16 planes)
__global__ __launch_bounds__(256) void im2col1_kernel(
    const float* __restrict__ x, unsigned short* __restrict__ Ah,
    unsigned short* __restrict__ Al)
{
    int t = blockIdx.x * 256 + threadIdx.x;
    int col = blockIdx.y;  // 0..383
    if (t >= 3000) return;
    int tap = col >> 7, i = col & 127;
    int src = t - 1 + tap;
    float v = (src >= 0 && src < 3000) ? x[(size_t)i * 3000 + src] : 0.0f;
    unsigned short h = f2bf(v);
    Ah[(size_t)t * 384 + col] = h;
    Al[(size_t)t * 384 + col] = f2bf(v - bf2f(h));
}

// A2[t][tap*1280+o] = g1[2t-1+tap][o], t in [0,1500)  (hi/lo bf16 planes)
__global__ __launch_bounds__(256) void im2col2_kernel(
    const float* __restrict__ g1, unsigned short* __restrict__ Ah,
    unsigned short* __restrict__ Al)
{
    int col = blockIdx.x * 256 + threadIdx.x;  // 0..3839
    int t = blockIdx.y;
    if (col >= 3840) return;
    int tap = col / 1280, o = col - tap * 1280;
    int src = 2 * t - 1 + tap;
    float v = (src >= 0 && src < 3000) ? g1[(size_t)src * 1280 + o] : 0.0f;
    unsigned short h = f2bf(v);
    Ah[(size_t)t * 3840 + col] = h;
    Al[(size_t)t * 3840 + col] = f2bf(v - bf2f(h));
}

// out[o][tap*C+i] = w[o][i][tap]  (hi/lo bf16 planes)
__global__ __launch_bounds__(256) void wreorder_kernel(
    const float* __restrict__ w, unsigned short* __restrict__ woh,
    unsigned short* __restrict__ wol, int C)
{
    int o = blockIdx.x;
    int KC = 3 * C;
    const float* wr = w + (size_t)o * KC;
    for (int col = threadIdx.x; col < KC; col += 256) {
        int tap = col / C, i = col - tap * C;
        float v = wr[i * 3 + tap];
        unsigned short h = f2bf(v);
        woh[(size_t)o * KC + col] = h;
        wol[(size_t)o * KC + col] = f2bf(v - bf2f(h));
    }
}

// C[m][n] = gelu(A[m,:].W[n,:] + bias[n])
// 128x128 tile, 4 waves (2x2, each 64x64), LDS double-buffered via
// global_load_lds width=16 (m97 structure), XCD-swizzled flat grid.
// Planes staged per buffer: 0=Ah 1=Al 2=Bh 3=Bl, each [128][32] bf16.
__global__ __launch_bounds__(256, 2) void gemm_conv_bf16x3(
    const unsigned short* __restrict__ Ah, const unsigned short* __restrict__ Al,
    const unsigned short* __restrict__ Wh, const unsigned short* __restrict__ Wl,
    const float* __restrict__ bias,
    float* __restrict__ out, int M, int N, int K, int nTilesN)
{
    __shared__ unsigned short lds[2][4][128][32];   // 64 KB
    int tid = threadIdx.x;
    int lane = tid & 63;
    int wv = tid >> 6;
    int l15 = lane & 15, quad = lane >> 4;
    int wm = wv >> 1, wn = wv & 1;   // 2x2 wave grid

    // bijective XCD swizzle (gridDim.x % 8 == 0)
    int nwg = gridDim.x;
    int cpx = nwg >> 3;
    int bid = blockIdx.x;
    int swz = (bid & 7) * cpx + (bid >> 3);
    int bx = swz % nTilesN, by = swz / nTilesN;
    int m0 = by * 128, n0 = bx * 128;

    // wave wv stages plane wv: 8 chunks x 1024B; lane -> row (lane>>2), 16B slot (lane&3)
    const unsigned short* splane = (wv == 0) ? Ah : (wv == 1) ? Al : (wv == 2) ? Wh : Wl;
    int rbase = (wv < 2) ? m0 : n0;
    int rlim  = (wv < 2) ? M : N;
    const unsigned short* srcp[8];
    #pragma unroll
    for (int c = 0; c < 8; c++) {
        int row = rbase + c * 16 + (lane >> 2);
        if (row >= rlim) row = rlim - 1;
        srcp[c] = splane + (size_t)row * K + (lane & 3) * 8;
    }

    auto stage = [&](int nb, int k0) {
        char* lbase = (char*)&lds[nb][wv][0][0];
        #pragma unroll
        for (int c = 0; c < 8; c++)
            gload_lds16(srcp[c] + k0, lbase + c * 1024);
    };

    v4f acc[4][4];
    #pragma unroll
    for (int i = 0; i < 4; i++)
        #pragma unroll
        for (int j = 0; j < 4; j++) acc[i][j] = (v4f){0.0f, 0.0f, 0.0f, 0.0f};

    int nsteps = K >> 5;
    stage(0, 0);
    __syncthreads();   // buf0 staged (vmcnt drain at barrier)
    int cur = 0;
    for (int t = 0; t < nsteps; t++) {
        if (t + 1 < nsteps) stage(cur ^ 1, (t + 1) * 32);   // prefetch next (hidden under MFMA)
        v8s ah[4], al2[4], bh[4], bl[4];
        #pragma unroll
        for (int i = 0; i < 4; i++) {
            ah[i]  = *(const v8s*)&lds[cur][0][wm * 64 + i * 16 + l15][quad * 8];
            al2[i] = *(const v8s*)&lds[cur][1][wm * 64 + i * 16 + l15][quad * 8];
            bh[i]  = *(const v8s*)&lds[cur][2][wn * 64 + i * 16 + l15][quad * 8];
            bl[i]  = *(const v8s*)&lds[cur][3][wn * 64 + i * 16 + l15][quad * 8];
        }
        #pragma unroll
        for (int i = 0; i < 4; i++)
            #pragma unroll
            for (int j = 0; j < 4; j++) {
                acc[i][j] = __builtin_amdgcn_mfma_f32_16x16x32_bf16(ah[i],  bh[j], acc[i][j], 0, 0, 0);
                acc[i][j] = __builtin_amdgcn_mfma_f32_16x16x32_bf16(al2[i], bh[j], acc[i][j], 0, 0, 0);
                acc[i][j] = __builtin_amdgcn_mfma_f32_16x16x32_bf16(ah[i],  bl[j], acc[i][j], 0, 0, 0);
            }
        __syncthreads();   // drains prefetch + all reads of lds[cur] done
        cur ^= 1;
    }

    #pragma unroll
    for (int i = 0; i < 4; i++) {
        #pragma unroll
        for (int j = 0; j < 4; j++) {
            int n = n0 + wn * 64 + j * 16 + l15;
            float bn = bias[n];
            #pragma unroll
            for (int r = 0; r < 4; r++) {
                int m = m0 + wm * 64 + i * 16 + quad * 4 + r;
                if (m < M) {
                    out[(size_t)m * N + n] = gelu_tanh(acc[i][j][r] + bn);
                }
            }
        }
    }
}

// Split-K variant for conv2: grid = nTilesM*nTilesN*SK (SK=3), each block
// accumulates a K-chunk and writes an f32 partial slice (p0/p1/p2).
__global__ __launch_bounds__(256, 2) void gemm_conv_splitk(
    const unsigned short* __restrict__ Ah, const unsigned short* __restrict__ Al,
    const unsigned short* __restrict__ Wh, const unsigned short* __restrict__ Wl,
    float* __restrict__ p0, float* __restrict__ p1, float* __restrict__ p2,
    int M, int N, int Krow, int Kchunk, int nTilesN, int nTilesM)
{
    __shared__ unsigned short lds[2][4][128][32];   // 64 KB
    int tid = threadIdx.x;
    int lane = tid & 63;
    int wv = tid >> 6;
    int l15 = lane & 15, quad = lane >> 4;
    int wm = wv >> 1, wn = wv & 1;

    int nwg = gridDim.x;
    int cpx = nwg >> 3;
    int bid = blockIdx.x;
    int swz = (bid & 7) * cpx + (bid >> 3);
    int bx = swz % nTilesN;
    int t2 = swz / nTilesN;
    int by = t2 % nTilesM;
    int ks = t2 / nTilesM;
    int m0 = by * 128, n0 = bx * 128;
    int kofs = ks * Kchunk;

    const unsigned short* splane = (wv == 0) ? Ah : (wv == 1) ? Al : (wv == 2) ? Wh : Wl;
    int rbase = (wv < 2) ? m0 : n0;
    int rlim  = (wv < 2) ? M : N;
    const unsigned short* srcp[8];
    #pragma unroll
    for (int c = 0; c < 8; c++) {
        int row = rbase + c * 16 + (lane >> 2);
        if (row >= rlim) row = rlim - 1;
        srcp[c] = splane + (size_t)row * Krow + (lane & 3) * 8 + kofs;
    }

    auto stage = [&](int nb, int k0) {
        char* lbase = (char*)&lds[nb][wv][0][0];
        #pragma unroll
        for (int c = 0; c < 8; c++)
            gload_lds16(srcp[c] + k0, lbase + c * 1024);
    };

    v4f acc[4][4];
    #pragma unroll
    for (int i = 0; i < 4; i++)
        #pragma unroll
        for (int j = 0; j < 4; j++) acc[i][j] = (v4f){0.0f, 0.0f, 0.0f, 0.0f};

    int nsteps = Kchunk >> 5;
    stage(0, 0);
    __syncthreads();
    int cur = 0;
    for (int t = 0; t < nsteps; t++) {
        if (t + 1 < nsteps) stage(cur ^ 1, (t + 1) * 32);
        v8s ah[4], al2[4], bh[4], bl[4];
        #pragma unroll
        for (int i = 0; i < 4; i++) {
            ah[i]  = *(const v8s*)&lds[cur][0][wm * 64 + i * 16 + l15][quad * 8];
            al2[i] = *(const v8s*)&lds[cur][1][wm * 64 + i * 16 + l15][quad * 8];
            bh[i]  = *(const v8s*)&lds[cur][2][wn * 64 + i * 16 + l15][quad * 8];
            bl[i]  = *(const v8s*)&lds[cur][3][wn * 64 + i * 16 + l15][quad * 8];
        }
        #pragma unroll
        for (int i = 0; i < 4; i++)
            #pragma unroll
            for (int j = 0; j < 4; j++) {
                acc[i][j] = __builtin_amdgcn_mfma_f32_16x16x32_bf16(ah[i],  bh[j], acc[i][j], 0, 0, 0);
                acc[i][j] = __builtin_amdgcn_mfma_f32_16x16x32_bf16(al2[i], bh[j], acc[i][j], 0, 0, 0);
                acc[i][j] = __builtin_amdgcn_mfma_f32_16x16x32_bf16(ah[i],  bl[j], acc[i][j], 0, 0, 0);
            }
        __syncthreads();
        cur ^= 1;
    }

    float* pp = (ks == 0) ? p0 : (ks == 1) ? p1 : p2;
    #pragma unroll
    for (int i = 0; i < 4; i++) {
        #pragma unroll
        for (int j = 0; j < 4; j++) {
            int n = n0 + wn * 64 + j * 16 + l15;
            #pragma unroll
            for (int r = 0; r < 4; r++) {
                int m = m0 + wm * 64 + i * 16 + quad * 4 + r;
                if (m < M) pp[(size_t)m * N + n] = acc[i][j][r];
            }
        }
    }
}

// conv2 epilogue: out = gelu(p0+p1+p2+bias) + pos   (flat float4 over [1500][1280])
__global__ __launch_bounds__(256) void conv2_epi_kernel(
    const float* __restrict__ p0, const float* __restrict__ p1,
    const float* __restrict__ p2, const float* __restrict__ bias,
    const float* __restrict__ pos, float* __restrict__ out)
{
    int idx = blockIdx.x * 256 + threadIdx.x;    // 0 .. 1500*320-1
    float4 a = ((const float4*)p0)[idx];
    float4 b = ((const float4*)p1)[idx];
    float4 c = ((const float4*)p2)[idx];
    float4 bb = ((const float4*)bias)[idx % 320];
    float4 pp = ((const float4*)pos)[idx];
    float4 o;
    o.x = gelu_tanh(a.x + b.x + c.x + bb.x) + pp.x;
    o.y = gelu_tanh(a.y + b.y + c.y + bb.y) + pp.y;
    o.z = gelu_tanh(a.z + b.z + c.z + bb.z) + pp.z;
    o.w = gelu_tanh(a.w + b.w + c.w + bb.w) + pp.w;
    ((float4*)out)[idx] = o;
}

// ---------------- quantization kernels ----------------

// per-row weight quant: block per row, float4
__global__ __launch_bounds__(256) void wquant_kernel(
    const float* __restrict__ w, int8_t* __restrict__ qw,
    float* __restrict__ ws, int K)
{
    int r = blockIdx.x;
    int tid = threadIdx.x;
    __shared__ float sm4[4];
    const float4* wr = (const float4*)(w + (size_t)r * K);
    int n4 = K >> 2;
    float mx = 0.0f;
    for (int i = tid; i < n4; i += 256) {
        float4 v = wr[i];
        mx = fmaxf(mx, fmaxf(fmaxf(fabsf(v.x), fabsf(v.y)), fmaxf(fabsf(v.z), fabsf(v.w))));
    }
    mx = block_max(mx, sm4);
    float sc = fmaxf(mx / 127.0f, 1e-8f);
    if (tid == 0) ws[r] = sc;
    float rs = 1.0f / sc;
    char4* qr = (char4*)(qw + (size_t)r * K);
    for (int i = tid; i < n4; i += 256) {
        float4 v = wr[i];
        char4 q;
        q.x = (int8_t)fminf(fmaxf(rintf(v.x * rs), -128.0f), 127.0f);
        q.y = (int8_t)fminf(fmaxf(rintf(v.y * rs), -128.0f), 127.0f);
        q.z = (int8_t)fminf(fmaxf(rintf(v.z * rs), -128.0f), 127.0f);
        q.w = (int8_t)fminf(fmaxf(rintf(v.w * rs), -128.0f), 127.0f);
        qr[i] = q;
    }
}

// RMSNorm + per-token quant, D=1280, block per token
__global__ __launch_bounds__(256) void rmsnorm_quant_kernel(
    const float* __restrict__ x, const float* __restrict__ w,
    const float* __restrict__ b, int8_t* __restrict__ q,
    float* __restrict__ sx)
{
    int s = blockIdx.x;
    int tid = threadIdx.x;
    __shared__ float sm4[4];
    const float* xr = x + (size_t)s * D_MODEL;
    float v[5];
    float ss = 0.0f;
    for (int i = 0; i < 5; i++) {
        float t = xr[tid + 256 * i];
        v[i] = t;
        ss += t * t;
    }
    ss = block_sum(ss, sm4);
    float inv = rsqrtf(ss * (1.0f / 1280.0f) + 1e-6f);
    float mx = 0.0f;
    for (int i = 0; i < 5; i++) {
        int idx = tid + 256 * i;
        float t = v[i] * inv * w[idx] + b[idx];
        v[i] = t;
        mx = fmaxf(mx, fabsf(t));
    }
    mx = block_max(mx, sm4);
    float sc = fmaxf(mx / 127.0f, 1e-8f);
    if (tid == 0) sx[s] = sc;
    float rs = 1.0f / sc;
    for (int i = 0; i < 5; i++) {
        float qv = rintf(v[i] * rs);
        qv = fminf(fmaxf(qv, -128.0f), 127.0f);
        q[(size_t)s * D_MODEL + tid + 256 * i] = (int8_t)qv;
    }
}

// per-token quant (optionally fused gelu); block per token
template <bool GELU>
__global__ __launch_bounds__(256) void quant_kernel(
    const float* __restrict__ x, int8_t* __restrict__ q,
    float* __restrict__ sx, int Dm)
{
    int s = blockIdx.x;
    int tid = threadIdx.x;
    __shared__ float sm4[4];
    const float4* xr = (const float4*)(x + (size_t)s * Dm);
    int n4 = Dm >> 2;
    float mx = 0.0f;
    for (int i = tid; i < n4; i += 256) {
        float4 t = xr[i];
        if (GELU) { t.x = gelu_tanh(t.x); t.y = gelu_tanh(t.y); t.z = gelu_tanh(t.z); t.w = gelu_tanh(t.w); }
        mx = fmaxf(mx, fmaxf(fmaxf(fabsf(t.x), fabsf(t.y)), fmaxf(fabsf(t.z), fabsf(t.w))));
    }
    mx = block_max(mx, sm4);
    float sc = fmaxf(mx / 127.0f, 1e-8f);
    if (tid == 0) sx[s] = sc;
    float rs = 1.0f / sc;
    char4* qr = (char4*)(q + (size_t)s * Dm);
    for (int i = tid; i < n4; i += 256) {
        float4 t = xr[i];
        if (GELU) { t.x = gelu_tanh(t.x); t.y = gelu_tanh(t.y); t.z = gelu_tanh(t.z); t.w = gelu_tanh(t.w); }
        char4 qq;
        qq.x = (int8_t)fminf(fmaxf(rintf(t.x * rs), -128.0f), 127.0f);
        qq.y = (int8_t)fminf(fmaxf(rintf(t.y * rs), -128.0f), 127.0f);
        qq.z = (int8_t)fminf(fmaxf(rintf(t.z * rs), -128.0f), 127.0f);
        qq.w = (int8_t)fminf(fmaxf(rintf(t.w * rs), -128.0f), 127.0f);
        qr[i] = qq;
    }
}

// ---------------- int8 GEMM via MFMA ----------------
// out[m,n] = (sum_k qx[m,k]*qw[n,k]) * sx[m] * ws[n] + bias[n] (+ res[m,n])
__global__ __launch_bounds__(256) void gemm_w8a8_mfma(
    const int8_t* __restrict__ qx, const float* __restrict__ sx,
    const int8_t* __restrict__ qw, const float* __restrict__ ws,
    const float* __restrict__ bias, const float* __restrict__ res,
    float* __restrict__ out, int M, int O, int K)
{
    int lane = threadIdx.x & 63;
    int wv = threadIdx.x >> 6;
    int l15 = lane & 15;
    int quad = lane >> 4;
    int m_base = blockIdx.y * 64 + wv * 16;
    int n_base = blockIdx.x * 64;

    int ar = m_base + l15; if (ar >= M) ar = M - 1;
    const int8_t* ap = qx + (size_t)ar * K + quad * 16;
    const int8_t* bp = qw + (size_t)(n_base + l15) * K + quad * 16;
    size_t rowK16 = (size_t)16 * K;

    v4i acc0 = {0, 0, 0, 0}, acc1 = {0, 0, 0, 0}, acc2 = {0, 0, 0, 0}, acc3 = {0, 0, 0, 0};
    int nsteps = K >> 6;
    for (int s = 0; s < nsteps; s++) {
        v4i a  = *(const v4i*)(ap + s * 64);
        v4i b0 = *(const v4i*)(bp + s * 64);
        v4i b1 = *(const v4i*)(bp + rowK16 + s * 64);
        v4i b2 = *(const v4i*)(bp + 2 * rowK16 + s * 64);
        v4i b3 = *(const v4i*)(bp + 3 * rowK16 + s * 64);
        acc0 = __builtin_amdgcn_mfma_i32_16x16x64_i8(a, b0, acc0, 0, 0, 0);
        acc1 = __builtin_amdgcn_mfma_i32_16x16x64_i8(a, b1, acc1, 0, 0, 0);
        acc2 = __builtin_amdgcn_mfma_i32_16x16x64_i8(a, b2, acc2, 0, 0, 0);
        acc3 = __builtin_amdgcn_mfma_i32_16x16x64_i8(a, b3, acc3, 0, 0, 0);
    }

    float sxv[4];
    #pragma unroll
    for (int r = 0; r < 4; r++) {
        int m = m_base + quad * 4 + r;
        sxv[r] = (m < M) ? sx[m] : 0.0f;
    }
    v4i accs[4] = {acc0, acc1, acc2, acc3};
    #pragma unroll
    for (int nb = 0; nb < 4; nb++) {
        int n = n_base + nb * 16 + l15;
        float wn = ws[n];
        float bn = bias[n];
        #pragma unroll
        for (int r = 0; r < 4; r++) {
            int m = m_base + quad * 4 + r;
            if (m < M) {
                float y = (float)accs[nb][r] * sxv[r] * wn + bn;
                if (res) y += res[(size_t)m * O + n];
                out[(size_t)m * O + n] = y;
            }
        }
    }
}

// ---------------- attention: flash-style with split-bf16 MFMA ----------------
// grid (24 q-tiles, 20 heads), 256 threads (4 waves, 16 q-rows each).
// QK^T and PV on matrix cores with hi/lo bf16 split (f32-equivalent).
// qkv layout [S][3840] with q|k|v each [H][64].
// LDS rows padded to 72 elements (144 B): 16B-aligned v8s frags, no pow2 stride.
__global__ __launch_bounds__(256, 2) void attn_mfma_kernel(
    const float* __restrict__ qkv, float* __restrict__ ao)
{
    __shared__ ushort_t Kh[64][72], Kl[64][72];   // K tile [k][d]
    __shared__ ushort_t Vh[64][72], Vl[64][72];   // V tile transposed [d][k]
    __shared__ ushort_t Ph[64][72], Pl[64][72];   // P tile [q][k]
    int h = blockIdx.y;
    int q_tile = blockIdx.x;
    int tid = threadIdx.x;
    int lane = tid & 63;
    int wv = tid >> 6;
    int l15 = lane & 15, quad = lane >> 4;

    // ---- Q fragments to registers (hi/lo), A-operand layout ----
    int qg = q_tile * 64 + wv * 16 + l15;
    int qc = qg < S_LEN ? qg : S_LEN - 1;
    const float* qsrc = qkv + (size_t)qc * 3840 + h * 64;
    v8s qh[2], ql[2];
    #pragma unroll
    for (int ks = 0; ks < 2; ks++) {
        const float4* p4 = (const float4*)(qsrc + ks * 32 + quad * 8);
        float4 a = p4[0], b = p4[1];
        float f[8] = {a.x, a.y, a.z, a.w, b.x, b.y, b.z, b.w};
        #pragma unroll
        for (int j = 0; j < 8; j++) {
            unsigned short hh = f2bf(f[j]);
            qh[ks][j] = (short)hh;
            ql[ks][j] = (short)f2bf(f[j] - bf2f(hh));
        }
    }

    v4f O[4];
    #pragma unroll
    for (int nb = 0; nb < 4; nb++) O[nb] = (v4f){0.0f, 0.0f, 0.0f, 0.0f};
    float m_run[4], l_run[4];
    #pragma unroll
    for (int r = 0; r < 4; r++) { m_run[r] = -INFINITY; l_run[r] = 0.0f; }

    // staging thread mappings
    int sk = tid >> 2, sd = (tid & 3) * 16;          // K: row sk, 16 d's
    int vk = (tid & 15) * 4, vd = (tid >> 4) * 4;    // V: 4x4 block transpose

    for (int kt = 0; kt < 24; kt++) {
        int kbase = kt * 64;
        int krem = S_LEN - kbase;   // valid keys in this tile (>=28)

        __syncthreads();   // prev iter PV reads of V/P done (covers Q-load iter0)

        // ---- stage K tile [k][d] bf16 hi/lo ----
        {
            int kg2 = kbase + sk;
            int kc2 = kg2 < S_LEN ? kg2 : S_LEN - 1;
            const float* src = qkv + (size_t)kc2 * 3840 + 1280 + h * 64 + sd;
            float f[16];
            *(float4*)&f[0]  = ((const float4*)src)[0];
            *(float4*)&f[4]  = ((const float4*)src)[1];
            *(float4*)&f[8]  = ((const float4*)src)[2];
            *(float4*)&f[12] = ((const float4*)src)[3];
            v8s h0, h1, l0, l1;
            #pragma unroll
            for (int j = 0; j < 8; j++) {
                unsigned short u0 = f2bf(f[j]);
                unsigned short u1 = f2bf(f[8 + j]);
                h0[j] = (short)u0; l0[j] = (short)f2bf(f[j] - bf2f(u0));
                h1[j] = (short)u1; l1[j] = (short)f2bf(f[8 + j] - bf2f(u1));
            }
            *(v8s*)&Kh[sk][sd] = h0; *(v8s*)&Kh[sk][sd + 8] = h1;
            *(v8s*)&Kl[sk][sd] = l0; *(v8s*)&Kl[sk][sd + 8] = l1;
        }
        // ---- stage V tile transposed [d][k] bf16 hi/lo ----
        {
            float vals[4][4];
            #pragma unroll
            for (int i = 0; i < 4; i++) {
                int kg2 = kbase + vk + i;
                int kc2 = kg2 < S_LEN ? kg2 : S_LEN - 1;
                *(float4*)&vals[i][0] =
                    *(const float4*)(qkv + (size_t)kc2 * 3840 + 2560 + h * 64 + vd);
            }
            #pragma unroll
            for (int j = 0; j < 4; j++) {
                v4s hv, lv;
                #pragma unroll
                for (int i = 0; i < 4; i++) {
                    unsigned short u = f2bf(vals[i][j]);
                    hv[i] = (short)u;
                    lv[i] = (short)f2bf(vals[i][j] - bf2f(u));
                }
                *(v4s*)&Vh[vd + j][vk] = hv;
                *(v4s*)&Vl[vd + j][vk] = lv;
            }
        }
        __syncthreads();

        // ---- QK^T via MFMA: S[64q][64k], split hi/lo x3 ----
        v4f S[4];
        #pragma unroll
        for (int nb = 0; nb < 4; nb++) S[nb] = (v4f){0.0f, 0.0f, 0.0f, 0.0f};
        #pragma unroll
        for (int ks = 0; ks < 2; ks++) {
            #pragma unroll
            for (int nb = 0; nb < 4; nb++) {
                v8s kbh = *(const v8s*)&Kh[nb * 16 + l15][ks * 32 + quad * 8];
                v8s kbl = *(const v8s*)&Kl[nb * 16 + l15][ks * 32 + quad * 8];
                S[nb] = __builtin_amdgcn_mfma_f32_16x16x32_bf16(qh[ks], kbh, S[nb], 0, 0, 0);
                S[nb] = __builtin_amdgcn_mfma_f32_16x16x32_bf16(ql[ks], kbh, S[nb], 0, 0, 0);
                S[nb] = __builtin_amdgcn_mfma_f32_16x16x32_bf16(qh[ks], kbl, S[nb], 0, 0, 0);
            }
        }

        // scale + mask (C layout: row q = quad*4+r, col k = nb*16+l15)
        #pragma unroll
        for (int nb = 0; nb < 4; nb++) {
            bool valid = (nb * 16 + l15) < krem;
            #pragma unroll
            for (int r = 0; r < 4; r++) {
                float s = S[nb][r] * 0.125f;
                S[nb][r] = valid ? s : -INFINITY;
            }
        }

        // online softmax: reduce over cols = local (nb) + shfl over l15 group
        #pragma unroll
        for (int r = 0; r < 4; r++) {
            float t = fmaxf(fmaxf(S[0][r], S[1][r]), fmaxf(S[2][r], S[3][r]));
            #pragma unroll
            for (int msk = 1; msk < 16; msk <<= 1)
                t = fmaxf(t, __shfl_xor(t, msk, 64));
            float mn = fmaxf(m_run[r], t);
            float alpha = __expf(m_run[r] - mn);
            m_run[r] = mn;
            float rs = 0.0f;
            #pragma unroll
            for (int nb = 0; nb < 4; nb++) {
                float p = __expf(S[nb][r] - mn);
                S[nb][r] = p;
                rs += p;
            }
            #pragma unroll
            for (int msk = 1; msk < 16; msk <<= 1)
                rs += __shfl_xor(rs, msk, 64);
            l_run[r] = l_run[r] * alpha + rs;
            #pragma unroll
            for (int nb = 0; nb < 4; nb++) O[nb][r] *= alpha;
        }

        // store P hi/lo to LDS (rows wv*16 + quad*4 + r)
        #pragma unroll
        for (int nb = 0; nb < 4; nb++) {
            #pragma unroll
            for (int r = 0; r < 4; r++) {
                float p = S[nb][r];
                unsigned short hp = f2bf(p);
                Ph[wv * 16 + quad * 4 + r][nb * 16 + l15] = hp;
                Pl[wv * 16 + quad * 4 + r][nb * 16 + l15] = f2bf(p - bf2f(hp));
            }
        }
        __syncthreads();   // P visible; K reads done (V/P reads next)

        // ---- PV via MFMA: O[64q][64d] += P x V, split x3 ----
        #pragma unroll
        for (int ks = 0; ks < 2; ks++) {
            v8s pah = *(const v8s*)&Ph[wv * 16 + l15][ks * 32 + quad * 8];
            v8s pal = *(const v8s*)&Pl[wv * 16 + l15][ks * 32 + quad * 8];
            #pragma unroll
            for (int nb = 0; nb < 4; nb++) {
                v8s vbh = *(const v8s*)&Vh[nb * 16 + l15][ks * 32 + quad * 8];
                v8s vbl = *(const v8s*)&Vl[nb * 16 + l15][ks * 32 + quad * 8];
                O[nb] = __builtin_amdgcn_mfma_f32_16x16x32_bf16(pah, vbh, O[nb], 0, 0, 0);
                O[nb] = __builtin_amdgcn_mfma_f32_16x16x32_bf16(pal, vbh, O[nb], 0, 0, 0);
                O[nb] = __builtin_amdgcn_mfma_f32_16x16x32_bf16(pah, vbl, O[nb], 0, 0, 0);
            }
        }
    }

    // epilogue (C layout: row q = wv*16 + quad*4 + r, col d = nb*16 + l15)
    #pragma unroll
    for (int r = 0; r < 4; r++) {
        int qg2 = q_tile * 64 + wv * 16 + quad * 4 + r;
        if (qg2 < S_LEN) {
            float rl = 1.0f / l_run[r];
            #pragma unroll
            for (int nb = 0; nb < 4; nb++)
                ao[(size_t)qg2 * D_MODEL + h * 64 + nb * 16 + l15] = O[nb][r] * rl;
        }
    }
}

// ---------------- final pool + layernorm ----------------
__global__ __launch_bounds__(256) void pool_ln_kernel(
    const float* __restrict__ h, const float* __restrict__ w,
    const float* __restrict__ b, float* __restrict__ out)
{
    int t = blockIdx.x;
    int tid = threadIdx.x;
    __shared__ float sm4[4];
    const float* r0 = h + (size_t)(2 * t) * D_MODEL;
    const float* r1 = r0 + D_MODEL;
    float v[5];
    float s1 = 0.0f;
    for (int i = 0; i < 5; i++) {
        int idx = tid + 256 * i;
        float x = 0.5f * (r0[idx] + r1[idx]);
        v[i] = x;
        s1 += x;
    }
    float mu = block_sum(s1, sm4) * (1.0f / 1280.0f);
    float s2 = 0.0f;
    for (int i = 0; i < 5; i++) {
        float d = v[i] - mu;
        s2 += d * d;
    }
    float var = block_sum(s2, sm4) * (1.0f / 1280.0f);
    float inv = rsqrtf(var + 1e-5f);
    for (int i = 0; i < 5; i++) {
        int idx = tid + 256 * i;
        out[(size_t)t * D_MODEL + idx] = (v[i] - mu) * inv * w[idx] + b[idx];
    }
}

// ---------------- host ----------------

static inline size_t al256(size_t x) { return (x + 255) & ~(size_t)255; }

extern "C" void kernel_launch(void* const* d_in, const int* in_sizes, int n_in,
                              void* d_out, int out_size, void* d_ws, size_t ws_size,
                              hipStream_t stream) {
    const float* in_feat = (const float*)d_in[0];   // [1][128][3000]
    const float* conv1_w = (const float*)d_in[1];
    const float* conv1_b = (const float*)d_in[2];
    const float* conv2_w = (const float*)d_in[3];
    const float* conv2_b = (const float*)d_in[4];
    const float* pos_emb = (const float*)d_in[5];
    const float* ln1_w   = (const float*)d_in[6];
    const float* ln1_b   = (const float*)d_in[7];
    const float* qkv_w   = (const float*)d_in[8];
    const float* qkv_b   = (const float*)d_in[9];
    const float* out_w   = (const float*)d_in[10];
    const float* out_b   = (const float*)d_in[11];
    const float* ln2_w   = (const float*)d_in[12];
    const float* ln2_b   = (const float*)d_in[13];
    const float* fc1_w   = (const float*)d_in[14];
    const float* fc1_b   = (const float*)d_in[15];
    const float* fc2_w   = (const float*)d_in[16];
    const float* fc2_b   = (const float*)d_in[17];
    const float* lnf_w   = (const float*)d_in[18];
    const float* lnf_b   = (const float*)d_in[19];
    float* outp = (float*)d_out;

    char* ws = (char*)d_ws;
    size_t off = 0;
    auto carve = [&](size_t bytes) {
        void* p = ws + off;
        off += al256(bytes);
        return p;
    };
    float*  hA      = (float*)carve((size_t)S_LEN * D_MODEL * 4);
    float*  hB      = (float*)carve((size_t)S_LEN * D_MODEL * 4);
    float*  qkvbuf  = (float*)carve((size_t)S_LEN * 3840 * 4);       // also g1 / W2r
    float*  aobuf   = (float*)carve((size_t)S_LEN * D_MODEL * 4);    // also W1r
    float*  f1buf   = (float*)carve((size_t)S_LEN * FF_DIM * 4);     // also A2
    int8_t* q8      = (int8_t*)carve((size_t)S_LEN * FF_DIM);        // also A1
    float*  sx      = (float*)carve((size_t)S_LEN * 4);
    int8_t* qw_qkv  = (int8_t*)carve((size_t)3840 * 1280);
    float*  ws_qkv  = (float*)carve((size_t)3840 * 4);
    int8_t* qw_out  = (int8_t*)carve((size_t)1280 * 1280);
    float*  ws_out  = (float*)carve((size_t)1280 * 4);
    int8_t* qw_fc1  = (int8_t*)carve((size_t)5120 * 1280);
    float*  ws_fc1  = (float*)carve((size_t)5120 * 4);
    int8_t* qw_fc2  = (int8_t*)carve((size_t)1280 * 5120);
    float*  ws_fc2  = (float*)carve((size_t)1280 * 4);
    (void)ws_size; (void)n_in; (void)in_sizes; (void)out_size;

    // conv stem aliases (all consumed before the transformer loop starts)
    unsigned short* A1h = (unsigned short*)q8;            // 3000*384*2*2 = 4.6 MB  <= 7.68 MB
    unsigned short* A1l = A1h + (size_t)3000 * 384;
    unsigned short* W1h = (unsigned short*)aobuf;         // 1280*384*2*2 = 2.0 MB  <= 7.68 MB
    unsigned short* W1l = W1h + (size_t)1280 * 384;
    float* g1 = qkvbuf;                                   // 3000*1280*4 = 15.4 MB <= 23 MB
    unsigned short* A2h = (unsigned short*)f1buf;         // 1500*3840*2*2 = 23 MB <= 30.7 MB
    unsigned short* A2l = A2h + (size_t)1500 * 3840;
    unsigned short* W2h = (unsigned short*)qkvbuf;        // 1280*3840*2*2 = 19.7 MB <= 23 MB (after g1 consumed)
    unsigned short* W2l = W2h + (size_t)1280 * 3840;
    // conv2 split-K partial slices (each 1500*1280*4 = 7.68 MB, free during conv stem)
    float* P2a = hB;
    float* P2b = aobuf;           // W1h/W1l consumed by conv1 gemm before conv2 runs
    float* P2c = (float*)q8;      // A1h/A1l consumed by conv1 gemm before conv2 runs

    // conv1: im2col (K=384) + bf16x3 MFMA GEMM + gelu -> g1[3000][1280]
    im2col1_kernel<<<dim3(12, 384), 256, 0, stream>>>(in_feat, A1h, A1l);
    wreorder_kernel<<<1280, 256, 0, stream>>>(conv1_w, W1h, W1l, 128);
    gemm_conv_bf16x3<<<240, 256, 0, stream>>>(A1h, A1l, W1h, W1l, conv1_b, g1, 3000, 1280, 384, 10);
    // conv2: im2col (row concat, K=3840) + split-K=3 bf16x3 MFMA GEMM -> partials,
    // then epilogue gelu+bias+pos -> hA[1500][1280]
    im2col2_kernel<<<dim3(15, 1500), 256, 0, stream>>>(g1, A2h, A2l);
    wreorder_kernel<<<1280, 256, 0, stream>>>(conv2_w, W2h, W2l, 1280);
    gemm_conv_splitk<<<360, 256, 0, stream>>>(A2h, A2l, W2h, W2l, P2a, P2b, P2c,
                                              1500, 1280, 3840, 1280, 10, 12);
    conv2_epi_kernel<<<1875, 256, 0, stream>>>(P2a, P2b, P2c, conv2_b, pos_emb, hA);

    float* h = hA;
    float* hn = hB;
    const int mtiles = (S_LEN + 63) / 64;  // 24

    for (int l = 0; l < N_LAYER; l++) {
        // quantize this layer's weights
        wquant_kernel<<<3840, 256, 0, stream>>>(qkv_w + (size_t)l * 3840 * 1280, qw_qkv, ws_qkv, 1280);
        wquant_kernel<<<1280, 256, 0, stream>>>(out_w + (size_t)l * 1280 * 1280, qw_out, ws_out, 1280);
        wquant_kernel<<<5120, 256, 0, stream>>>(fc1_w + (size_t)l * 5120 * 1280, qw_fc1, ws_fc1, 1280);
        wquant_kernel<<<1280, 256, 0, stream>>>(fc2_w + (size_t)l * 1280 * 5120, qw_fc2, ws_fc2, 5120);

        // attention block
        rmsnorm_quant_kernel<<<S_LEN, 256, 0, stream>>>(h, ln1_w + l * D_MODEL, ln1_b + l * D_MODEL, q8, sx);
        gemm_w8a8_mfma<<<dim3(60, mtiles), 256, 0, stream>>>(q8, sx, qw_qkv, ws_qkv,
            qkv_b + (size_t)l * 3840, nullptr, qkvbuf, S_LEN, 3840, 1280);
        attn_mfma_kernel<<<dim3(24, N_HEAD), 256, 0, stream>>>(qkvbuf, aobuf);
        quant_kernel<false><<<S_LEN, 256, 0, stream>>>(aobuf, q8, sx, D_MODEL);
        gemm_w8a8_mfma<<<dim3(20, mtiles), 256, 0, stream>>>(q8, sx, qw_out, ws_out,
            out_b + (size_t)l * 1280, h, hn, S_LEN, 1280, 1280);
        { float* t = h; h = hn; hn = t; }

        // MLP block
        rmsnorm_quant_kernel<<<S_LEN, 256, 0, stream>>>(h, ln2_w + l * D_MODEL, ln2_b + l * D_MODEL, q8, sx);
        gemm_w8a8_mfma<<<dim3(80, mtiles), 256, 0, stream>>>(q8, sx, qw_fc1, ws_fc1,
            fc1_b + (size_t)l * 5120, nullptr, f1buf, S_LEN, 5120, 1280);
        quant_kernel<true><<<S_LEN, 256, 0, stream>>>(f1buf, q8, sx, FF_DIM);
        gemm_w8a8_mfma<<<dim3(20, mtiles), 256, 0, stream>>>(q8, sx, qw_fc2, ws_fc2,
            fc2_b + (size_t)l * 1280, h, hn, S_LEN, 1280, 5120);
        { float* t = h; h = hn; hn = t; }
    }

    pool_ln_kernel<<<750, 256, 0, stream>>>(h, lnf_w, lnf_b, outp);
}